// Round 1
// baseline (2687.483 us; speedup 1.0000x reference)
//
#include <hip/hip_runtime.h>
#include <math.h>

#define BB 2
#define NN 2048
#define EE 1024
#define HH 16
#define DD 64
#define SCALE 0.125f

// ---------------- tiny init + mask flag ----------------
__global__ void k_zero_flag(int* flag) { *flag = 0; }

__global__ void k_maskflag(const int* __restrict__ mask, int* __restrict__ flag) {
    int tid = blockIdx.x * blockDim.x + threadIdx.x;
    int has = 0;
    const int total = NN * NN;
    for (int i = tid; i < total; i += gridDim.x * blockDim.x)
        has |= (mask[i] == 0);
    if (__any(has) && (threadIdx.x & 63) == 0)
        atomicOr(flag, 1);
}

// ---------------- generic tiled fp32 GEMM: C = (A [+ alpha*addA]) @ W + bias --------
// A [M,K] row-major, W [K,Nc] row-major, C [M,Nc]. BM=BN=64, BK=16, 256 thr, 4x4/thread.
__global__ __launch_bounds__(256) void k_gemm(
    const float* __restrict__ A, const float* __restrict__ addA,
    const float* __restrict__ alphap,
    const float* __restrict__ W, const float* __restrict__ bias,
    float* __restrict__ C, int M, int Nc, int K)
{
    __shared__ float As[16][64];   // [k][m]
    __shared__ float Bs[16][68];   // [k][n], pad for bank spread, rows 16B-aligned
    const int t = threadIdx.x;
    const int tx = t & 15, ty = t >> 4;
    const int m0 = blockIdx.y * 64, n0 = blockIdx.x * 64;
    const int ar = t >> 2, ac4 = t & 3;    // A staging: row, f4 col
    const int bk = t >> 4, bc4 = t & 15;   // W staging
    float alpha = 0.f;
    if (addA) alpha = alphap[0];

    float acc[4][4] = {};
    for (int k0 = 0; k0 < K; k0 += 16) {
        float4 av = *(const float4*)&A[(size_t)(m0 + ar) * K + k0 + ac4 * 4];
        if (addA) {
            float4 xv = *(const float4*)&addA[(size_t)(m0 + ar) * K + k0 + ac4 * 4];
            av.x += alpha * xv.x; av.y += alpha * xv.y;
            av.z += alpha * xv.z; av.w += alpha * xv.w;
        }
        float4 bv = *(const float4*)&W[(size_t)(k0 + bk) * Nc + n0 + bc4 * 4];
        __syncthreads();   // previous iteration's reads done
        As[ac4 * 4 + 0][ar] = av.x;
        As[ac4 * 4 + 1][ar] = av.y;
        As[ac4 * 4 + 2][ar] = av.z;
        As[ac4 * 4 + 3][ar] = av.w;
        *(float4*)&Bs[bk][bc4 * 4] = bv;
        __syncthreads();
        #pragma unroll
        for (int kk = 0; kk < 16; kk++) {
            float4 a = *(const float4*)&As[kk][ty * 4];
            float4 b = *(const float4*)&Bs[kk][tx * 4];
            const float ai[4] = {a.x, a.y, a.z, a.w};
            const float bj[4] = {b.x, b.y, b.z, b.w};
            #pragma unroll
            for (int i = 0; i < 4; i++)
                #pragma unroll
                for (int j = 0; j < 4; j++)
                    acc[i][j] += ai[i] * bj[j];
        }
    }
    float4 bv = *(const float4*)&bias[n0 + tx * 4];
    const float bj[4] = {bv.x, bv.y, bv.z, bv.w};
    #pragma unroll
    for (int i = 0; i < 4; i++) {
        float4 o;
        o.x = acc[i][0] + bj[0]; o.y = acc[i][1] + bj[1];
        o.z = acc[i][2] + bj[2]; o.w = acc[i][3] + bj[3];
        *(float4*)&C[(size_t)(m0 + ty * 4 + i) * Nc + n0 + tx * 4] = o;
    }
}

// ---------------- attention helpers ----------------
// stage 64x64 tile (rows row0.., cols col0..col0+63 of src with row stride EE)
// into dst laid out [64][68] row-major
__device__ __forceinline__ void stage_rows(float* dst, const float* __restrict__ src,
                                           int row0, int col0, int t) {
    #pragma unroll
    for (int ch = 0; ch < 4; ch++) {
        int idx4 = t + ch * 256;
        int r = idx4 >> 4, c4 = idx4 & 15;
        float4 g = *(const float4*)&src[(size_t)(row0 + r) * EE + col0 + c4 * 4];
        *(float4*)&dst[r * 68 + c4 * 4] = g;
    }
}

// stage transposed: dst[d][j] = src[row0+j][col0+d], dst [64][68]
__device__ __forceinline__ void stage_trans(float* dst, const float* __restrict__ src,
                                            int row0, int col0, int t) {
    #pragma unroll
    for (int ch = 0; ch < 4; ch++) {
        int idx4 = t + ch * 256;
        int r = idx4 >> 4, c4 = idx4 & 15;
        float4 g = *(const float4*)&src[(size_t)(row0 + r) * EE + col0 + c4 * 4];
        dst[(c4 * 4 + 0) * 68 + r] = g.x;
        dst[(c4 * 4 + 1) * 68 + r] = g.y;
        dst[(c4 * 4 + 2) * 68 + r] = g.z;
        dst[(c4 * 4 + 3) * 68 + r] = g.w;
    }
}

// s[i][j] = sum_d Qs[ty*4+i][d] * Kt[d][tx*4+j]
__device__ __forceinline__ void s_tile(const float* Qs, const float* Kt,
                                       int ty, int tx, float s[4][4]) {
    #pragma unroll
    for (int i = 0; i < 4; i++)
        #pragma unroll
        for (int j = 0; j < 4; j++) s[i][j] = 0.f;
    #pragma unroll
    for (int d4 = 0; d4 < 16; d4++) {
        float4 q[4];
        #pragma unroll
        for (int i = 0; i < 4; i++)
            q[i] = *(const float4*)&Qs[(ty * 4 + i) * 68 + d4 * 4];
        #pragma unroll
        for (int u = 0; u < 4; u++) {
            float4 kt = *(const float4*)&Kt[(d4 * 4 + u) * 68 + tx * 4];
            const float kj[4] = {kt.x, kt.y, kt.z, kt.w};
            #pragma unroll
            for (int i = 0; i < 4; i++) {
                const float* qf = (const float*)&q[i];
                float qs = qf[u];
                #pragma unroll
                for (int j = 0; j < 4; j++) s[i][j] += qs * kj[j];
            }
        }
    }
}

// ---------------- softmax stats (m, 1/l) per (b,h,row) ----------------
__global__ __launch_bounds__(256) void k_stats(
    const float* __restrict__ qp, const float* __restrict__ kp,
    const int* __restrict__ mask, const int* __restrict__ flag,
    float* __restrict__ mbuf, float* __restrict__ lbuf)
{
    __shared__ float Qs[64 * 68];
    __shared__ float Kt[64 * 68];
    const int t = threadIdx.x, tx = t & 15, ty = t >> 4;
    const int it = blockIdx.x, bh = blockIdx.y;
    const int b = bh >> 4, h = bh & 15;
    const int i0 = it * 64;
    const int hasmask = *flag;

    stage_rows(Qs, qp + (size_t)b * NN * EE, i0, h * DD, t);
    float mr[4], lr[4];
    #pragma unroll
    for (int i = 0; i < 4; i++) { mr[i] = -INFINITY; lr[i] = 0.f; }

    for (int jt = 0; jt < 32; jt++) {
        __syncthreads();
        stage_trans(Kt, kp + (size_t)b * NN * EE, jt * 64, h * DD, t);
        __syncthreads();
        float s[4][4];
        s_tile(Qs, Kt, ty, tx, s);
        #pragma unroll
        for (int i = 0; i < 4; i++)
            #pragma unroll
            for (int j = 0; j < 4; j++) s[i][j] *= SCALE;
        if (hasmask) {
            #pragma unroll
            for (int i = 0; i < 4; i++)
                #pragma unroll
                for (int j = 0; j < 4; j++)
                    if (mask[(size_t)(i0 + ty * 4 + i) * NN + jt * 64 + tx * 4 + j] == 0)
                        s[i][j] = -INFINITY;
        }
        #pragma unroll
        for (int i = 0; i < 4; i++) {
            float mx = fmaxf(fmaxf(s[i][0], s[i][1]), fmaxf(s[i][2], s[i][3]));
            #pragma unroll
            for (int off = 1; off < 16; off <<= 1) mx = fmaxf(mx, __shfl_xor(mx, off));
            if (mx == -INFINITY) continue;   // fully-masked tile contributes nothing
            float sm = 0.f;
            #pragma unroll
            for (int j = 0; j < 4; j++) sm += expf(s[i][j] - mx);
            #pragma unroll
            for (int off = 1; off < 16; off <<= 1) sm += __shfl_xor(sm, off);
            float nm = fmaxf(mr[i], mx);
            lr[i] = lr[i] * expf(mr[i] - nm) + sm * expf(mx - nm);
            mr[i] = nm;
        }
    }
    if (tx == 0) {
        #pragma unroll
        for (int i = 0; i < 4; i++) {
            int row = bh * NN + i0 + ty * 4 + i;
            mbuf[row] = mr[i];
            lbuf[row] = 1.f / lr[i];
        }
    }
}

// ---------------- attention output per (b,h,row-tile) ----------------
__global__ __launch_bounds__(256) void k_attn_o(
    const float* __restrict__ qp, const float* __restrict__ kp, const float* __restrict__ vp,
    const int* __restrict__ mask, const int* __restrict__ flag,
    const float* __restrict__ mbuf, const float* __restrict__ lbuf,
    float* __restrict__ oatt)
{
    __shared__ float Qs[64 * 68];
    __shared__ float Kt[64 * 68];
    __shared__ float Vs[64 * 68];
    __shared__ float Ws[64 * 68];
    const int t = threadIdx.x, tx = t & 15, ty = t >> 4;
    const int it = blockIdx.x, bh = blockIdx.y;
    const int b = bh >> 4, h = bh & 15;
    const int i0 = it * 64;
    const int hasmask = *flag;

    stage_rows(Qs, qp + (size_t)b * NN * EE, i0, h * DD, t);
    float mr[4], li[4];
    #pragma unroll
    for (int i = 0; i < 4; i++) {
        int row = bh * NN + i0 + ty * 4 + i;
        mr[i] = mbuf[row];
        li[i] = lbuf[row];
    }
    float oacc[4][4] = {};

    for (int jt = 0; jt < 32; jt++) {
        __syncthreads();
        stage_trans(Kt, kp + (size_t)b * NN * EE, jt * 64, h * DD, t);
        stage_rows (Vs, vp + (size_t)b * NN * EE, jt * 64, h * DD, t);
        __syncthreads();
        float s[4][4];
        s_tile(Qs, Kt, ty, tx, s);
        #pragma unroll
        for (int i = 0; i < 4; i++) {
            #pragma unroll
            for (int j = 0; j < 4; j++) s[i][j] *= SCALE;
        }
        if (hasmask) {
            #pragma unroll
            for (int i = 0; i < 4; i++)
                #pragma unroll
                for (int j = 0; j < 4; j++)
                    if (mask[(size_t)(i0 + ty * 4 + i) * NN + jt * 64 + tx * 4 + j] == 0)
                        s[i][j] = -INFINITY;
        }
        #pragma unroll
        for (int i = 0; i < 4; i++) {
            float4 wv;
            wv.x = expf(s[i][0] - mr[i]) * li[i];
            wv.y = expf(s[i][1] - mr[i]) * li[i];
            wv.z = expf(s[i][2] - mr[i]) * li[i];
            wv.w = expf(s[i][3] - mr[i]) * li[i];
            *(float4*)&Ws[(ty * 4 + i) * 68 + tx * 4] = wv;
        }
        __syncthreads();
        #pragma unroll 4
        for (int j = 0; j < 64; j++) {
            float4 v4 = *(const float4*)&Vs[j * 68 + tx * 4];
            #pragma unroll
            for (int i = 0; i < 4; i++) {
                float w = Ws[(ty * 4 + i) * 68 + j];
                oacc[i][0] += w * v4.x; oacc[i][1] += w * v4.y;
                oacc[i][2] += w * v4.z; oacc[i][3] += w * v4.w;
            }
        }
    }
    #pragma unroll
    for (int i = 0; i < 4; i++) {
        float4 o = {oacc[i][0], oacc[i][1], oacc[i][2], oacc[i][3]};
        *(float4*)&oatt[(size_t)(b * NN + i0 + ty * 4 + i) * EE + h * DD + tx * 4] = o;
    }
}

// ---------------- wsum[b,i,j] = sum_h w ----------------
__global__ __launch_bounds__(256) void k_wsum(
    const float* __restrict__ qp, const float* __restrict__ kp,
    const int* __restrict__ mask, const int* __restrict__ flag,
    const float* __restrict__ mbuf, const float* __restrict__ lbuf,
    float* __restrict__ wsum)
{
    __shared__ float Qs[64 * 68];
    __shared__ float Kt[64 * 68];
    const int t = threadIdx.x, tx = t & 15, ty = t >> 4;
    const int jt = blockIdx.x, it = blockIdx.y, b = blockIdx.z;
    const int i0 = it * 64, j0 = jt * 64;
    const int hasmask = *flag;

    unsigned mbits = 0;
    if (hasmask) {
        #pragma unroll
        for (int i = 0; i < 4; i++)
            #pragma unroll
            for (int j = 0; j < 4; j++)
                if (mask[(size_t)(i0 + ty * 4 + i) * NN + j0 + tx * 4 + j] == 0)
                    mbits |= 1u << (i * 4 + j);
    }
    float wacc[4][4] = {};
    for (int h = 0; h < HH; h++) {
        __syncthreads();
        stage_rows (Qs, qp + (size_t)b * NN * EE, i0, h * DD, t);
        stage_trans(Kt, kp + (size_t)b * NN * EE, j0, h * DD, t);
        __syncthreads();
        float s[4][4];
        s_tile(Qs, Kt, ty, tx, s);
        const int bh = b * HH + h;
        #pragma unroll
        for (int i = 0; i < 4; i++) {
            float m = mbuf[bh * NN + i0 + ty * 4 + i];
            float li = lbuf[bh * NN + i0 + ty * 4 + i];
            #pragma unroll
            for (int j = 0; j < 4; j++) {
                if (!((mbits >> (i * 4 + j)) & 1u))
                    wacc[i][j] += expf(s[i][j] * SCALE - m) * li;
            }
        }
    }
    #pragma unroll
    for (int i = 0; i < 4; i++) {
        float4 o = {wacc[i][0], wacc[i][1], wacc[i][2], wacc[i][3]};
        *(float4*)&wsum[(size_t)b * NN * NN + (size_t)(i0 + ty * 4 + i) * NN + j0 + tx * 4] = o;
    }
}

// ---------------- launch ----------------
extern "C" void kernel_launch(void* const* d_in, const int* in_sizes, int n_in,
                              void* d_out, int out_size, void* d_ws, size_t ws_size,
                              hipStream_t stream) {
    const float* q    = (const float*)d_in[0];
    const float* k    = (const float*)d_in[1];
    const float* v    = (const float*)d_in[2];
    const int*   mask = (const int*)  d_in[3];
    const float* Wq   = (const float*)d_in[4];
    const float* bq   = (const float*)d_in[5];
    const float* Wkv  = (const float*)d_in[6];
    const float* bkv  = (const float*)d_in[7];
    const float* Wo   = (const float*)d_in[8];
    const float* bo   = (const float*)d_in[9];
    const float* alpha= (const float*)d_in[10];

    float* ws   = (float*)d_ws;
    float* qp   = ws;                       // 4096x1024
    float* kp   = ws + 4194304;             // 4096x1024
    float* vp   = ws + 8388608;             // 4096x1024
    float* mbuf = ws + 12582912;            // B*H*N
    float* lbuf = mbuf + 65536;             // B*H*N (stores 1/l)
    float* oatt = ws + 12713984;            // 4096x1024
    int*   flag = (int*)(ws + 16908288);

    float* out_o = (float*)d_out;           // [B,N,E]
    float* out_w = out_o + (size_t)BB * NN * EE;   // [B,N,N]

    k_zero_flag<<<1, 1, 0, stream>>>(flag);
    k_maskflag<<<1024, 256, 0, stream>>>(mask, flag);

    dim3 gg(EE / 64, (BB * NN) / 64);   // (16, 64)
    k_gemm<<<gg, 256, 0, stream>>>(q, nullptr, nullptr, Wq,  bq,  qp, BB * NN, EE, EE);
    k_gemm<<<gg, 256, 0, stream>>>(k, nullptr, nullptr, Wkv, bkv, kp, BB * NN, EE, EE);
    k_gemm<<<gg, 256, 0, stream>>>(v, nullptr, nullptr, Wkv, bkv, vp, BB * NN, EE, EE);

    k_stats <<<dim3(NN / 64, BB * HH), 256, 0, stream>>>(qp, kp, mask, flag, mbuf, lbuf);
    k_attn_o<<<dim3(NN / 64, BB * HH), 256, 0, stream>>>(qp, kp, vp, mask, flag, mbuf, lbuf, oatt);
    k_wsum  <<<dim3(NN / 64, NN / 64, BB), 256, 0, stream>>>(qp, kp, mask, flag, mbuf, lbuf, out_w);

    // out = (oatt + alpha*vp) @ Wo + bo
    k_gemm<<<gg, 256, 0, stream>>>(oatt, vp, alpha, Wo, bo, out_o, BB * NN, EE, EE);
}

// Round 3
// 1356.503 us; speedup vs baseline: 1.9812x; 1.9812x over previous
//
#include <hip/hip_runtime.h>
#include <math.h>

#define BB 2
#define NN 2048
#define EE 1024
#define HH 16
#define DD 64
#define SCALE 0.125f

// ---------------- tiny init + mask flag ----------------
__global__ void k_zero_flag(int* flag) { *flag = 0; }

__global__ void k_maskflag(const int* __restrict__ mask, int* __restrict__ flag) {
    int tid = blockIdx.x * blockDim.x + threadIdx.x;
    int has = 0;
    const int total = NN * NN;
    for (int i = tid; i < total; i += gridDim.x * blockDim.x)
        has |= (mask[i] == 0);
    if (__any(has) && (threadIdx.x & 63) == 0)
        atomicOr(flag, 1);
}

// ---------------- generic tiled fp32 GEMM: C = (A [+ alpha*addA]) @ W + bias --------
// A [M,K] row-major, W [K,Nc] row-major, C [M,Nc]. BM=BN=64, BK=16, 256 thr, 4x4/thread.
__global__ __launch_bounds__(256) void k_gemm(
    const float* __restrict__ A, const float* __restrict__ addA,
    const float* __restrict__ alphap,
    const float* __restrict__ W, const float* __restrict__ bias,
    float* __restrict__ C, int M, int Nc, int K)
{
    __shared__ float As[16][68];   // [k][m], pad->2-way writes
    __shared__ float Bs[16][68];   // [k][n]
    const int t = threadIdx.x;
    const int tx = t & 15, ty = t >> 4;
    const int m0 = blockIdx.y * 64, n0 = blockIdx.x * 64;
    const int ar = t >> 2, ac4 = t & 3;    // A staging: row, f4 col
    const int bk = t >> 4, bc4 = t & 15;   // W staging
    float alpha = 0.f;
    if (addA) alpha = alphap[0];

    float acc[4][4] = {};
    for (int k0 = 0; k0 < K; k0 += 16) {
        float4 av = *(const float4*)&A[(size_t)(m0 + ar) * K + k0 + ac4 * 4];
        if (addA) {
            float4 xv = *(const float4*)&addA[(size_t)(m0 + ar) * K + k0 + ac4 * 4];
            av.x += alpha * xv.x; av.y += alpha * xv.y;
            av.z += alpha * xv.z; av.w += alpha * xv.w;
        }
        float4 bv = *(const float4*)&W[(size_t)(k0 + bk) * Nc + n0 + bc4 * 4];
        __syncthreads();   // previous iteration's reads done
        As[ac4 * 4 + 0][ar] = av.x;
        As[ac4 * 4 + 1][ar] = av.y;
        As[ac4 * 4 + 2][ar] = av.z;
        As[ac4 * 4 + 3][ar] = av.w;
        *(float4*)&Bs[bk][bc4 * 4] = bv;
        __syncthreads();
        #pragma unroll
        for (int kk = 0; kk < 16; kk++) {
            float4 a = *(const float4*)&As[kk][ty * 4];
            float4 b = *(const float4*)&Bs[kk][tx * 4];
            const float ai[4] = {a.x, a.y, a.z, a.w};
            const float bj[4] = {b.x, b.y, b.z, b.w};
            #pragma unroll
            for (int i = 0; i < 4; i++)
                #pragma unroll
                for (int j = 0; j < 4; j++)
                    acc[i][j] += ai[i] * bj[j];
        }
    }
    float4 bv = *(const float4*)&bias[n0 + tx * 4];
    const float bj[4] = {bv.x, bv.y, bv.z, bv.w};
    #pragma unroll
    for (int i = 0; i < 4; i++) {
        float4 o;
        o.x = acc[i][0] + bj[0]; o.y = acc[i][1] + bj[1];
        o.z = acc[i][2] + bj[2]; o.w = acc[i][3] + bj[3];
        *(float4*)&C[(size_t)(m0 + ty * 4 + i) * Nc + n0 + tx * 4] = o;
    }
}

// ---------------- GEMM writing transposed output: CT[n][m] = (A@W + bias)[m][n] -----
__global__ __launch_bounds__(256) void k_gemm_t(
    const float* __restrict__ A,
    const float* __restrict__ W, const float* __restrict__ bias,
    float* __restrict__ CT, int M, int Nc, int K)
{
    __shared__ float As[16][68];
    __shared__ float Bs[16][68];
    const int t = threadIdx.x;
    const int tx = t & 15, ty = t >> 4;
    const int m0 = blockIdx.y * 64, n0 = blockIdx.x * 64;
    const int ar = t >> 2, ac4 = t & 3;
    const int bk = t >> 4, bc4 = t & 15;

    float acc[4][4] = {};
    for (int k0 = 0; k0 < K; k0 += 16) {
        float4 av = *(const float4*)&A[(size_t)(m0 + ar) * K + k0 + ac4 * 4];
        float4 bv = *(const float4*)&W[(size_t)(k0 + bk) * Nc + n0 + bc4 * 4];
        __syncthreads();
        As[ac4 * 4 + 0][ar] = av.x;
        As[ac4 * 4 + 1][ar] = av.y;
        As[ac4 * 4 + 2][ar] = av.z;
        As[ac4 * 4 + 3][ar] = av.w;
        *(float4*)&Bs[bk][bc4 * 4] = bv;
        __syncthreads();
        #pragma unroll
        for (int kk = 0; kk < 16; kk++) {
            float4 a = *(const float4*)&As[kk][ty * 4];
            float4 b = *(const float4*)&Bs[kk][tx * 4];
            const float ai[4] = {a.x, a.y, a.z, a.w};
            const float bj[4] = {b.x, b.y, b.z, b.w};
            #pragma unroll
            for (int i = 0; i < 4; i++)
                #pragma unroll
                for (int j = 0; j < 4; j++)
                    acc[i][j] += ai[i] * bj[j];
        }
    }
    #pragma unroll
    for (int j = 0; j < 4; j++) {
        float bj = bias[n0 + tx * 4 + j];
        float4 o = {acc[0][j] + bj, acc[1][j] + bj, acc[2][j] + bj, acc[3][j] + bj};
        *(float4*)&CT[(size_t)(n0 + tx * 4 + j) * M + m0 + ty * 4] = o;
    }
}

// ---------------- stage a 64x64 tile row-major (rows of src -> rows of dst[64][64]) --
__device__ __forceinline__ void stage64(float* dst, const float* __restrict__ src,
                                        size_t stride, int t) {
    #pragma unroll
    for (int ch = 0; ch < 4; ch++) {
        int idx4 = t + ch * 256;
        int r = idx4 >> 4, c4 = idx4 & 15;
        *(float4*)&dst[r * 64 + c4 * 4] = *(const float4*)&src[(size_t)r * stride + c4 * 4];
    }
}

// s[i][j] += sum_d Qt[d][ty*4+i] * Kt[d][tx*4+j]; both tiles [64(d)][64(col)]
__device__ __forceinline__ void s_tile_t(const float* Qt, const float* Kt,
                                         int ty, int tx, float s[4][4]) {
    #pragma unroll
    for (int i = 0; i < 4; i++)
        #pragma unroll
        for (int j = 0; j < 4; j++) s[i][j] = 0.f;
    #pragma unroll 8
    for (int d = 0; d < 64; d++) {
        float4 a = *(const float4*)&Qt[d * 64 + ty * 4];
        float4 b = *(const float4*)&Kt[d * 64 + tx * 4];
        const float ai[4] = {a.x, a.y, a.z, a.w};
        const float bj[4] = {b.x, b.y, b.z, b.w};
        #pragma unroll
        for (int i = 0; i < 4; i++)
            #pragma unroll
            for (int j = 0; j < 4; j++)
                s[i][j] += ai[i] * bj[j];
    }
}

// ---------------- fused flash attention: O + (m, 1/l) stats ----------------
__global__ __launch_bounds__(256) void k_attn(
    const float* __restrict__ qpT, const float* __restrict__ kpT,
    const float* __restrict__ vp,
    const int* __restrict__ mask, const int* __restrict__ flag,
    float* __restrict__ mbuf, float* __restrict__ lbuf, float* __restrict__ oatt)
{
    __shared__ float Qt[64 * 64];
    __shared__ float Kt[64 * 64];
    __shared__ float Vs[64 * 64];
    __shared__ float Ws[64 * 64];   // XOR-swizzled: col' = col ^ ((row&7)<<2)
    const int t = threadIdx.x, tx = t & 15, ty = t >> 4;
    const int it = blockIdx.x, bh = blockIdx.y;
    const int b = bh >> 4, h = bh & 15;
    const int i0 = it * 64;
    const int hasmask = *flag;

    stage64(Qt, qpT + ((size_t)b * EE + h * DD) * NN + i0, NN, t);

    float m[4], l[4];
    float oacc[4][4] = {};
    #pragma unroll
    for (int i = 0; i < 4; i++) { m[i] = -INFINITY; l[i] = 0.f; }

    for (int jt = 0; jt < 32; jt++) {
        __syncthreads();
        stage64(Kt, kpT + ((size_t)b * EE + h * DD) * NN + jt * 64, NN, t);
        stage64(Vs, vp + ((size_t)(b * NN + jt * 64)) * EE + h * DD, EE, t);
        __syncthreads();
        float s[4][4];
        s_tile_t(Qt, Kt, ty, tx, s);
        #pragma unroll
        for (int i = 0; i < 4; i++)
            #pragma unroll
            for (int j = 0; j < 4; j++) s[i][j] *= SCALE;
        if (hasmask) {
            #pragma unroll
            for (int i = 0; i < 4; i++) {
                int4 mv = *(const int4*)&mask[(size_t)(i0 + ty * 4 + i) * NN + jt * 64 + tx * 4];
                if (mv.x == 0) s[i][0] = -INFINITY;
                if (mv.y == 0) s[i][1] = -INFINITY;
                if (mv.z == 0) s[i][2] = -INFINITY;
                if (mv.w == 0) s[i][3] = -INFINITY;
            }
        }
        #pragma unroll
        for (int i = 0; i < 4; i++) {
            float mx = fmaxf(fmaxf(s[i][0], s[i][1]), fmaxf(s[i][2], s[i][3]));
            #pragma unroll
            for (int off = 1; off < 16; off <<= 1) mx = fmaxf(mx, __shfl_xor(mx, off));
            float nm = fmaxf(m[i], mx);
            float4 p;
            float psum, scale;
            if (nm == -INFINITY) {
                p.x = p.y = p.z = p.w = 0.f; psum = 0.f; scale = 1.f;
            } else {
                p.x = __expf(s[i][0] - nm);
                p.y = __expf(s[i][1] - nm);
                p.z = __expf(s[i][2] - nm);
                p.w = __expf(s[i][3] - nm);
                psum = p.x + p.y + p.z + p.w;
                #pragma unroll
                for (int off = 1; off < 16; off <<= 1) psum += __shfl_xor(psum, off);
                scale = __expf(m[i] - nm);   // m=-inf -> 0, correct
            }
            l[i] = l[i] * scale + psum;
            m[i] = nm;
            oacc[i][0] *= scale; oacc[i][1] *= scale;
            oacc[i][2] *= scale; oacc[i][3] *= scale;
            int row = ty * 4 + i;
            *(float4*)&Ws[row * 64 + ((tx * 4) ^ (((row & 7)) << 2))] = p;
        }
        __syncthreads();
        #pragma unroll 4
        for (int j4 = 0; j4 < 16; j4++) {
            float4 w[4];
            #pragma unroll
            for (int i = 0; i < 4; i++) {
                int row = ty * 4 + i;
                w[i] = *(const float4*)&Ws[row * 64 + ((j4 * 4) ^ ((row & 7) << 2))];
            }
            #pragma unroll
            for (int jj = 0; jj < 4; jj++) {
                float4 v4 = *(const float4*)&Vs[(j4 * 4 + jj) * 64 + tx * 4];
                #pragma unroll
                for (int i = 0; i < 4; i++) {
                    float wx = ((const float*)&w[i])[jj];
                    oacc[i][0] += wx * v4.x; oacc[i][1] += wx * v4.y;
                    oacc[i][2] += wx * v4.z; oacc[i][3] += wx * v4.w;
                }
            }
        }
    }
    #pragma unroll
    for (int i = 0; i < 4; i++) {
        float li = 1.f / l[i];
        float4 o = {oacc[i][0] * li, oacc[i][1] * li, oacc[i][2] * li, oacc[i][3] * li};
        *(float4*)&oatt[(size_t)(b * NN + i0 + ty * 4 + i) * EE + h * DD + tx * 4] = o;
        if (tx == 0) {
            int row = bh * NN + i0 + ty * 4 + i;
            mbuf[row] = m[i];
            lbuf[row] = li;
        }
    }
}

// ---------------- wsum[b,i,j] = sum_h w ----------------
__global__ __launch_bounds__(256, 4) void k_wsum(
    const float* __restrict__ qpT, const float* __restrict__ kpT,
    const int* __restrict__ mask, const int* __restrict__ flag,
    const float* __restrict__ mbuf, const float* __restrict__ lbuf,
    float* __restrict__ wsum)
{
    __shared__ float Qt[64 * 64];
    __shared__ float Kt[64 * 64];
    __shared__ float Ms[16 * 64];
    __shared__ float Ls[16 * 64];
    const int t = threadIdx.x, tx = t & 15, ty = t >> 4;
    const int jt = blockIdx.x, it = blockIdx.y, b = blockIdx.z;
    const int i0 = it * 64, j0 = jt * 64;
    const int hasmask = *flag;

    #pragma unroll
    for (int ch = 0; ch < 4; ch++) {
        int idx = t + ch * 256;                 // h = idx>>6, r = idx&63
        size_t g = ((size_t)b * HH + (idx >> 6)) * NN + i0 + (idx & 63);
        Ms[idx] = mbuf[g];
        Ls[idx] = lbuf[g];
    }

    unsigned mbits = 0;
    if (hasmask) {
        #pragma unroll
        for (int i = 0; i < 4; i++) {
            int4 mv = *(const int4*)&mask[(size_t)(i0 + ty * 4 + i) * NN + j0 + tx * 4];
            if (mv.x == 0) mbits |= 1u << (i * 4 + 0);
            if (mv.y == 0) mbits |= 1u << (i * 4 + 1);
            if (mv.z == 0) mbits |= 1u << (i * 4 + 2);
            if (mv.w == 0) mbits |= 1u << (i * 4 + 3);
        }
    }

    float wacc[4][4] = {};
    for (int h = 0; h < HH; h++) {
        __syncthreads();
        stage64(Qt, qpT + ((size_t)b * EE + h * DD) * NN + i0, NN, t);
        stage64(Kt, kpT + ((size_t)b * EE + h * DD) * NN + j0, NN, t);
        __syncthreads();
        float s[4][4];
        s_tile_t(Qt, Kt, ty, tx, s);
        #pragma unroll
        for (int i = 0; i < 4; i++) {
            float mi = Ms[h * 64 + ty * 4 + i];
            float li = Ls[h * 64 + ty * 4 + i];
            #pragma unroll
            for (int j = 0; j < 4; j++) {
                if (!((mbits >> (i * 4 + j)) & 1u))
                    wacc[i][j] += __expf(fmaf(s[i][j], SCALE, -mi)) * li;
            }
        }
    }
    #pragma unroll
    for (int i = 0; i < 4; i++) {
        float4 o = {wacc[i][0], wacc[i][1], wacc[i][2], wacc[i][3]};
        *(float4*)&wsum[(size_t)b * NN * NN + (size_t)(i0 + ty * 4 + i) * NN + j0 + tx * 4] = o;
    }
}

// ---------------- launch ----------------
extern "C" void kernel_launch(void* const* d_in, const int* in_sizes, int n_in,
                              void* d_out, int out_size, void* d_ws, size_t ws_size,
                              hipStream_t stream) {
    const float* q    = (const float*)d_in[0];
    const float* k    = (const float*)d_in[1];
    const float* v    = (const float*)d_in[2];
    const int*   mask = (const int*)  d_in[3];
    const float* Wq   = (const float*)d_in[4];
    const float* bq   = (const float*)d_in[5];
    const float* Wkv  = (const float*)d_in[6];
    const float* bkv  = (const float*)d_in[7];
    const float* Wo   = (const float*)d_in[8];
    const float* bo   = (const float*)d_in[9];
    const float* alpha= (const float*)d_in[10];

    float* ws   = (float*)d_ws;
    float* qpT  = ws;                       // [B][E][N]
    float* kpT  = ws + 4194304;             // [B][E][N]
    float* vp   = ws + 8388608;             // [B][N][E]
    float* oatt = ws + 12582912;            // [B][N][E]
    float* mbuf = ws + 16777216;            // B*H*N
    float* lbuf = ws + 16842752;            // B*H*N (1/l)
    int*   flag = (int*)(ws + 16908288);

    float* out_o = (float*)d_out;                  // [B,N,E]
    float* out_w = out_o + (size_t)BB * NN * EE;   // [B,N,N]

    k_zero_flag<<<1, 1, 0, stream>>>(flag);
    k_maskflag<<<1024, 256, 0, stream>>>(mask, flag);

    dim3 gg(EE / 64, (BB * NN) / 64);   // (16, 64)
    k_gemm_t<<<gg, 256, 0, stream>>>(q, Wq,  bq,  qpT, BB * NN, EE, EE);
    k_gemm_t<<<gg, 256, 0, stream>>>(k, Wkv, bkv, kpT, BB * NN, EE, EE);
    k_gemm  <<<gg, 256, 0, stream>>>(v, nullptr, nullptr, Wkv, bkv, vp, BB * NN, EE, EE);

    k_attn<<<dim3(NN / 64, BB * HH), 256, 0, stream>>>(qpT, kpT, vp, mask, flag, mbuf, lbuf, oatt);
    k_wsum<<<dim3(NN / 64, NN / 64, BB), 256, 0, stream>>>(qpT, kpT, mask, flag, mbuf, lbuf, out_w);

    // out = (oatt + alpha*vp) @ Wo + bo
    k_gemm<<<gg, 256, 0, stream>>>(oatt, vp, alpha, Wo, bo, out_o, BB * NN, EE, EE);
}

// Round 4
// 691.362 us; speedup vs baseline: 3.8872x; 1.9621x over previous
//
#include <hip/hip_runtime.h>
#include <math.h>

#define BB 2
#define NN 2048
#define EE 1024
#define HH 16
#define DD 64
#define SCALE 0.125f

typedef __attribute__((ext_vector_type(8))) short bf16x8;
typedef __attribute__((ext_vector_type(4))) float f32x4;

#define MFMA16(a,b,c) __builtin_amdgcn_mfma_f32_16x16x32_bf16((a),(b),(c),0,0,0)

__device__ __forceinline__ ushort f2bf(float x){
    unsigned u = __float_as_uint(x);
    return (ushort)((u + 0x7fffu + ((u>>16)&1u)) >> 16);
}
__device__ __forceinline__ float bf2f(ushort h){ return __uint_as_float(((unsigned)h)<<16); }

union U4 { uint4 v; ushort s[8]; };

// ---------------- tiny init + mask flag ----------------
__global__ void k_zero_flag(int* flag) { *flag = 0; }

__global__ void k_maskflag(const int* __restrict__ mask, int* __restrict__ flag) {
    int tid = blockIdx.x * blockDim.x + threadIdx.x;
    int has = 0;
    const int total = NN * NN;
    for (int i = tid; i < total; i += gridDim.x * blockDim.x)
        has |= (mask[i] == 0);
    if (__any(has) && (threadIdx.x & 63) == 0)
        atomicOr(flag, 1);
}

// ---------------- weight transpose + split: W[K][Nc] -> WT_hi/lo[Nc][K] ----------
__global__ __launch_bounds__(256) void k_convW(const float* __restrict__ W,
                                               ushort* __restrict__ Thi,
                                               ushort* __restrict__ Tlo) {
    __shared__ float T[64][65];
    const int t = threadIdx.x;
    const int n0 = blockIdx.x * 64, k0 = blockIdx.y * 64;
    #pragma unroll
    for (int ch = 0; ch < 4; ch++) {
        int idx = t + ch * 256;
        int r = idx >> 4, c4 = idx & 15;
        float4 g = *(const float4*)&W[(size_t)(k0 + r) * EE + n0 + c4 * 4];
        T[r][c4 * 4 + 0] = g.x; T[r][c4 * 4 + 1] = g.y;
        T[r][c4 * 4 + 2] = g.z; T[r][c4 * 4 + 3] = g.w;
    }
    __syncthreads();
    #pragma unroll
    for (int ch = 0; ch < 4; ch++) {
        int idx = t + ch * 256;
        int nl = idx >> 4, k4 = idx & 15;
        ushort4 h4, l4;
        float x0 = T[k4 * 4 + 0][nl], x1 = T[k4 * 4 + 1][nl];
        float x2 = T[k4 * 4 + 2][nl], x3 = T[k4 * 4 + 3][nl];
        h4.x = f2bf(x0); l4.x = f2bf(x0 - bf2f(h4.x));
        h4.y = f2bf(x1); l4.y = f2bf(x1 - bf2f(h4.y));
        h4.z = f2bf(x2); l4.z = f2bf(x2 - bf2f(h4.z));
        h4.w = f2bf(x3); l4.w = f2bf(x3 - bf2f(h4.w));
        size_t o = (size_t)(n0 + nl) * EE + k0 + k4 * 4;
        *(ushort4*)&Thi[o] = h4;
        *(ushort4*)&Tlo[o] = l4;
    }
}

// ---------------- MFMA GEMM: C = (A [+ alpha*addA]) @ W + bias ----------------
// A [4096][1024] f32 (split on the fly), W given as WT_hi/lo [1024][1024] bf16.
// WF32: write f32 C; WBF: write (C*cscale) as hi/lo bf16.
template<int WF32, int WBF>
__global__ __launch_bounds__(256) void k_mgemm(
    const float* __restrict__ A, const float* __restrict__ addA,
    const float* __restrict__ alphap,
    const ushort* __restrict__ BTh, const ushort* __restrict__ BTl,
    const float* __restrict__ bias, float cscale,
    float* __restrict__ Cf, ushort* __restrict__ Chi, ushort* __restrict__ Clo)
{
    __shared__ __align__(16) ushort Ah[128 * 40];
    __shared__ __align__(16) ushort Al[128 * 40];
    __shared__ __align__(16) ushort Bh[128 * 40];
    __shared__ __align__(16) ushort Bl[128 * 40];
    const int t = threadIdx.x;
    const int m0 = blockIdx.y * 128, n0 = blockIdx.x * 128;
    const int w = t >> 6, wr = (w >> 1) * 64, wc = (w & 1) * 64;
    const int ln = t & 15, lg = (t >> 4) & 3;
    const int sr = t >> 1, sh = (t & 1) * 16;   // staging: row, k-half
    const float alpha = addA ? alphap[0] : 0.f;

    f32x4 acc[4][4];
    #pragma unroll
    for (int i = 0; i < 4; i++)
        #pragma unroll
        for (int j = 0; j < 4; j++) acc[i][j] = (f32x4){0.f, 0.f, 0.f, 0.f};

    for (int k0 = 0; k0 < EE; k0 += 32) {
        float av[16];
        {
            const float4* ap = (const float4*)(A + (size_t)(m0 + sr) * EE + k0 + sh);
            #pragma unroll
            for (int i = 0; i < 4; i++) {
                float4 g = ap[i];
                av[i * 4 + 0] = g.x; av[i * 4 + 1] = g.y;
                av[i * 4 + 2] = g.z; av[i * 4 + 3] = g.w;
            }
            if (addA) {
                const float4* xp = (const float4*)(addA + (size_t)(m0 + sr) * EE + k0 + sh);
                #pragma unroll
                for (int i = 0; i < 4; i++) {
                    float4 g = xp[i];
                    av[i * 4 + 0] += alpha * g.x; av[i * 4 + 1] += alpha * g.y;
                    av[i * 4 + 2] += alpha * g.z; av[i * 4 + 3] += alpha * g.w;
                }
            }
        }
        const ushort* bph = BTh + (size_t)(n0 + sr) * EE + k0 + sh;
        const ushort* bpl = BTl + (size_t)(n0 + sr) * EE + k0 + sh;
        uint4 bh0 = *(const uint4*)bph, bh1 = *(const uint4*)(bph + 8);
        uint4 bl0 = *(const uint4*)bpl, bl1 = *(const uint4*)(bpl + 8);
        __syncthreads();   // previous iteration's reads done
        #pragma unroll
        for (int half = 0; half < 2; half++) {
            U4 ph, pl;
            #pragma unroll
            for (int i = 0; i < 8; i++) {
                float x = av[half * 8 + i];
                ushort h = f2bf(x);
                ph.s[i] = h;
                pl.s[i] = f2bf(x - bf2f(h));
            }
            *(uint4*)&Ah[sr * 40 + sh + half * 8] = ph.v;
            *(uint4*)&Al[sr * 40 + sh + half * 8] = pl.v;
        }
        *(uint4*)&Bh[sr * 40 + sh] = bh0;
        *(uint4*)&Bh[sr * 40 + sh + 8] = bh1;
        *(uint4*)&Bl[sr * 40 + sh] = bl0;
        *(uint4*)&Bl[sr * 40 + sh + 8] = bl1;
        __syncthreads();
        bf16x8 af[4], alf[4], bf[4], blf[4];
        #pragma unroll
        for (int mt = 0; mt < 4; mt++) {
            af[mt]  = *(const bf16x8*)&Ah[(wr + mt * 16 + ln) * 40 + lg * 8];
            alf[mt] = *(const bf16x8*)&Al[(wr + mt * 16 + ln) * 40 + lg * 8];
        }
        #pragma unroll
        for (int nt = 0; nt < 4; nt++) {
            bf[nt]  = *(const bf16x8*)&Bh[(wc + nt * 16 + ln) * 40 + lg * 8];
            blf[nt] = *(const bf16x8*)&Bl[(wc + nt * 16 + ln) * 40 + lg * 8];
        }
        #pragma unroll
        for (int mt = 0; mt < 4; mt++)
            #pragma unroll
            for (int nt = 0; nt < 4; nt++) {
                acc[mt][nt] = MFMA16(af[mt],  bf[nt],  acc[mt][nt]);
                acc[mt][nt] = MFMA16(af[mt],  blf[nt], acc[mt][nt]);
                acc[mt][nt] = MFMA16(alf[mt], bf[nt],  acc[mt][nt]);
            }
    }
    #pragma unroll
    for (int nt = 0; nt < 4; nt++) {
        const int col = n0 + wc + nt * 16 + ln;
        const float bv = bias[col];
        #pragma unroll
        for (int mt = 0; mt < 4; mt++)
            #pragma unroll
            for (int j = 0; j < 4; j++) {
                const int row = m0 + wr + mt * 16 + 4 * lg + j;
                float val = acc[mt][nt][j] + bv;
                if (WF32) Cf[(size_t)row * EE + col] = val;
                if (WBF) {
                    float sv = val * cscale;
                    ushort h = f2bf(sv);
                    Chi[(size_t)row * EE + col] = h;
                    Clo[(size_t)row * EE + col] = f2bf(sv - bf2f(h));
                }
            }
    }
}

// ---------------- vp f32 [B*N][E] -> vT_hi/lo [B][E][N] ----------------
__global__ __launch_bounds__(256) void k_transV(const float* __restrict__ vp,
                                                ushort* __restrict__ vTh,
                                                ushort* __restrict__ vTl) {
    __shared__ float T[64][65];
    const int t = threadIdx.x;
    const int n0 = blockIdx.x * 64, e0 = blockIdx.y * 64, b = blockIdx.z;
    #pragma unroll
    for (int ch = 0; ch < 4; ch++) {
        int idx = t + ch * 256;
        int nl = idx >> 4, e4 = idx & 15;
        float4 g = *(const float4*)&vp[(size_t)(b * NN + n0 + nl) * EE + e0 + e4 * 4];
        T[nl][e4 * 4 + 0] = g.x; T[nl][e4 * 4 + 1] = g.y;
        T[nl][e4 * 4 + 2] = g.z; T[nl][e4 * 4 + 3] = g.w;
    }
    __syncthreads();
    const int el = t >> 2, nq = t & 3;
    U4 h0, h1, l0, l1;
    #pragma unroll
    for (int i = 0; i < 8; i++) {
        float x = T[nq * 16 + i][el];
        ushort h = f2bf(x);
        h0.s[i] = h; l0.s[i] = f2bf(x - bf2f(h));
    }
    #pragma unroll
    for (int i = 0; i < 8; i++) {
        float x = T[nq * 16 + 8 + i][el];
        ushort h = f2bf(x);
        h1.s[i] = h; l1.s[i] = f2bf(x - bf2f(h));
    }
    size_t o = ((size_t)b * EE + e0 + el) * NN + n0 + nq * 16;
    *(uint4*)&vTh[o] = h0.v; *(uint4*)&vTh[o + 8] = h1.v;
    *(uint4*)&vTl[o] = l0.v; *(uint4*)&vTl[o + 8] = l1.v;
}

// ---------------- MFMA flash attention ----------------
__global__ __launch_bounds__(256) void k_attn(
    const ushort* __restrict__ qph, const ushort* __restrict__ qpl,
    const ushort* __restrict__ kph, const ushort* __restrict__ kpl,
    const ushort* __restrict__ vTh, const ushort* __restrict__ vTl,
    const int* __restrict__ mask, const int* __restrict__ flag,
    float* __restrict__ mbuf, float* __restrict__ lbuf, float* __restrict__ oatt)
{
    __shared__ __align__(16) ushort Kh[64 * 72], Kl[64 * 72];
    __shared__ __align__(16) ushort Vh[64 * 72], Vl[64 * 72];
    __shared__ __align__(16) ushort Ph[64 * 72];
    const int t = threadIdx.x;
    const int it = blockIdx.x, bh = blockIdx.y;
    const int b = bh >> 4, h = bh & 15;
    const int i0 = it * 64;
    const int w = t >> 6, ln = t & 15, lg = (t >> 4) & 3;
    const int hasmask = *flag;

    bf16x8 qh[2], ql[2];
    {
        const size_t qo = ((size_t)(b * NN) + i0 + w * 16 + ln) * EE + h * DD;
        #pragma unroll
        for (int ks = 0; ks < 2; ks++) {
            qh[ks] = *(const bf16x8*)&qph[qo + ks * 32 + lg * 8];
            ql[ks] = *(const bf16x8*)&qpl[qo + ks * 32 + lg * 8];
        }
    }
    float m[4], l[4];
    f32x4 oacc[4];
    #pragma unroll
    for (int r = 0; r < 4; r++) { m[r] = -INFINITY; l[r] = 0.f; }
    #pragma unroll
    for (int df = 0; df < 4; df++) oacc[df] = (f32x4){0.f, 0.f, 0.f, 0.f};

    const int sq = t >> 2, sc = (t & 3) * 16;
    for (int jt = 0; jt < 32; jt++) {
        const int j0 = jt * 64;
        __syncthreads();
        {
            const size_t ko = ((size_t)(b * NN) + j0 + sq) * EE + h * DD + sc;
            *(uint4*)&Kh[sq * 72 + sc]     = *(const uint4*)&kph[ko];
            *(uint4*)&Kh[sq * 72 + sc + 8] = *(const uint4*)&kph[ko + 8];
            *(uint4*)&Kl[sq * 72 + sc]     = *(const uint4*)&kpl[ko];
            *(uint4*)&Kl[sq * 72 + sc + 8] = *(const uint4*)&kpl[ko + 8];
            const size_t vo = ((size_t)b * EE + h * DD + sq) * NN + j0 + sc;
            *(uint4*)&Vh[sq * 72 + sc]     = *(const uint4*)&vTh[vo];
            *(uint4*)&Vh[sq * 72 + sc + 8] = *(const uint4*)&vTh[vo + 8];
            *(uint4*)&Vl[sq * 72 + sc]     = *(const uint4*)&vTl[vo];
            *(uint4*)&Vl[sq * 72 + sc + 8] = *(const uint4*)&vTl[vo + 8];
        }
        __syncthreads();
        f32x4 s[4];
        #pragma unroll
        for (int kf = 0; kf < 4; kf++) {
            f32x4 sv = (f32x4){0.f, 0.f, 0.f, 0.f};
            #pragma unroll
            for (int ks = 0; ks < 2; ks++) {
                bf16x8 k8  = *(const bf16x8*)&Kh[(kf * 16 + ln) * 72 + ks * 32 + lg * 8];
                bf16x8 kl8 = *(const bf16x8*)&Kl[(kf * 16 + ln) * 72 + ks * 32 + lg * 8];
                sv = MFMA16(qh[ks], k8,  sv);
                sv = MFMA16(qh[ks], kl8, sv);
                sv = MFMA16(ql[ks], k8,  sv);
            }
            s[kf] = sv;
        }
        if (hasmask) {
            #pragma unroll
            for (int kf = 0; kf < 4; kf++)
                #pragma unroll
                for (int r = 0; r < 4; r++)
                    if (mask[(size_t)(i0 + w * 16 + 4 * lg + r) * NN + j0 + kf * 16 + ln] == 0)
                        s[kf][r] = -INFINITY;
        }
        #pragma unroll
        for (int r = 0; r < 4; r++) {
            float mx = fmaxf(fmaxf(s[0][r], s[1][r]), fmaxf(s[2][r], s[3][r]));
            #pragma unroll
            for (int off = 1; off < 16; off <<= 1) mx = fmaxf(mx, __shfl_xor(mx, off));
            float nm = fmaxf(m[r], mx);
            float sc_, psum;
            ushort pb0, pb1, pb2, pb3;
            if (nm == -INFINITY) {
                sc_ = 1.f; psum = 0.f; pb0 = pb1 = pb2 = pb3 = 0;
            } else {
                sc_ = __expf(m[r] - nm);
                float p0 = __expf(s[0][r] - nm), p1 = __expf(s[1][r] - nm);
                float p2 = __expf(s[2][r] - nm), p3 = __expf(s[3][r] - nm);
                pb0 = f2bf(p0); pb1 = f2bf(p1); pb2 = f2bf(p2); pb3 = f2bf(p3);
                psum = p0 + p1 + p2 + p3;
                #pragma unroll
                for (int off = 1; off < 16; off <<= 1) psum += __shfl_xor(psum, off);
            }
            l[r] = l[r] * sc_ + psum;
            m[r] = nm;
            #pragma unroll
            for (int df = 0; df < 4; df++) oacc[df][r] *= sc_;
            const int prow = (w * 16 + 4 * lg + r) * 72;
            Ph[prow + 0  + ln] = pb0;
            Ph[prow + 16 + ln] = pb1;
            Ph[prow + 32 + ln] = pb2;
            Ph[prow + 48 + ln] = pb3;
        }
        __syncthreads();
        #pragma unroll
        for (int ks = 0; ks < 2; ks++) {
            bf16x8 pf = *(const bf16x8*)&Ph[(w * 16 + ln) * 72 + ks * 32 + lg * 8];
            #pragma unroll
            for (int df = 0; df < 4; df++) {
                bf16x8 vh8 = *(const bf16x8*)&Vh[(df * 16 + ln) * 72 + ks * 32 + lg * 8];
                bf16x8 vl8 = *(const bf16x8*)&Vl[(df * 16 + ln) * 72 + ks * 32 + lg * 8];
                oacc[df] = MFMA16(pf, vh8, oacc[df]);
                oacc[df] = MFMA16(pf, vl8, oacc[df]);
            }
        }
    }
    #pragma unroll
    for (int r = 0; r < 4; r++) {
        float li = 1.f / l[r];
        const int q = i0 + w * 16 + 4 * lg + r;
        #pragma unroll
        for (int df = 0; df < 4; df++)
            oatt[((size_t)(b * NN) + q) * EE + h * DD + df * 16 + ln] = oacc[df][r] * li;
        if (ln == 0) {
            mbuf[(size_t)bh * NN + q] = m[r];
            lbuf[(size_t)bh * NN + q] = li;
        }
    }
}

// ---------------- wsum[b,i,j] = sum_h exp(s - m) * linv ----------------
__global__ __launch_bounds__(256) void k_wsum(
    const ushort* __restrict__ qph, const ushort* __restrict__ qpl,
    const ushort* __restrict__ kph, const ushort* __restrict__ kpl,
    const int* __restrict__ mask, const int* __restrict__ flag,
    const float* __restrict__ mbuf, const float* __restrict__ lbuf,
    float* __restrict__ wsum)
{
    __shared__ __align__(16) ushort Qh[64 * 72], Ql[64 * 72];
    __shared__ __align__(16) ushort Kh[64 * 72], Kl[64 * 72];
    __shared__ float Ms[16 * 64], Ls[16 * 64];
    const int t = threadIdx.x;
    const int jt = blockIdx.x, it = blockIdx.y, b = blockIdx.z;
    const int i0 = it * 64, j0 = jt * 64;
    const int w = t >> 6, ln = t & 15, lg = (t >> 4) & 3;
    const int hasmask = *flag;

    #pragma unroll
    for (int ch = 0; ch < 4; ch++) {
        int idx = t + ch * 256;
        int h_ = idx >> 6, q_ = idx & 63;
        Ms[idx] = mbuf[((size_t)b * HH + h_) * NN + i0 + q_];
        Ls[idx] = lbuf[((size_t)b * HH + h_) * NN + i0 + q_];
    }
    unsigned mbits = 0;
    if (hasmask) {
        #pragma unroll
        for (int kf = 0; kf < 4; kf++)
            #pragma unroll
            for (int r = 0; r < 4; r++)
                if (mask[(size_t)(i0 + w * 16 + 4 * lg + r) * NN + j0 + kf * 16 + ln] == 0)
                    mbits |= 1u << (kf * 4 + r);
    }
    float wacc[4][4] = {};   // [kf][r]
    const int sq = t >> 2, sc = (t & 3) * 16;
    for (int h = 0; h < HH; h++) {
        __syncthreads();
        {
            const size_t qo = ((size_t)(b * NN) + i0 + sq) * EE + h * DD + sc;
            *(uint4*)&Qh[sq * 72 + sc]     = *(const uint4*)&qph[qo];
            *(uint4*)&Qh[sq * 72 + sc + 8] = *(const uint4*)&qph[qo + 8];
            *(uint4*)&Ql[sq * 72 + sc]     = *(const uint4*)&qpl[qo];
            *(uint4*)&Ql[sq * 72 + sc + 8] = *(const uint4*)&qpl[qo + 8];
            const size_t ko = ((size_t)(b * NN) + j0 + sq) * EE + h * DD + sc;
            *(uint4*)&Kh[sq * 72 + sc]     = *(const uint4*)&kph[ko];
            *(uint4*)&Kh[sq * 72 + sc + 8] = *(const uint4*)&kph[ko + 8];
            *(uint4*)&Kl[sq * 72 + sc]     = *(const uint4*)&kpl[ko];
            *(uint4*)&Kl[sq * 72 + sc + 8] = *(const uint4*)&kpl[ko + 8];
        }
        __syncthreads();
        bf16x8 q8[2], ql8[2];
        #pragma unroll
        for (int ks = 0; ks < 2; ks++) {
            q8[ks]  = *(const bf16x8*)&Qh[(w * 16 + ln) * 72 + ks * 32 + lg * 8];
            ql8[ks] = *(const bf16x8*)&Ql[(w * 16 + ln) * 72 + ks * 32 + lg * 8];
        }
        #pragma unroll
        for (int kf = 0; kf < 4; kf++) {
            f32x4 sv = (f32x4){0.f, 0.f, 0.f, 0.f};
            #pragma unroll
            for (int ks = 0; ks < 2; ks++) {
                bf16x8 k8  = *(const bf16x8*)&Kh[(kf * 16 + ln) * 72 + ks * 32 + lg * 8];
                bf16x8 kl8 = *(const bf16x8*)&Kl[(kf * 16 + ln) * 72 + ks * 32 + lg * 8];
                sv = MFMA16(q8[ks], k8,  sv);
                sv = MFMA16(q8[ks], kl8, sv);
                sv = MFMA16(ql8[ks], k8, sv);
            }
            #pragma unroll
            for (int r = 0; r < 4; r++) {
                if (!((mbits >> (kf * 4 + r)) & 1u)) {
                    int q = w * 16 + 4 * lg + r;
                    wacc[kf][r] += __expf(sv[r] - Ms[h * 64 + q]) * Ls[h * 64 + q];
                }
            }
        }
    }
    #pragma unroll
    for (int kf = 0; kf < 4; kf++)
        #pragma unroll
        for (int r = 0; r < 4; r++)
            wsum[(size_t)b * NN * NN + (size_t)(i0 + w * 16 + 4 * lg + r) * NN + j0 + kf * 16 + ln]
                = wacc[kf][r];
}

// ---------------- launch ----------------
extern "C" void kernel_launch(void* const* d_in, const int* in_sizes, int n_in,
                              void* d_out, int out_size, void* d_ws, size_t ws_size,
                              hipStream_t stream) {
    const float* q    = (const float*)d_in[0];
    const float* k    = (const float*)d_in[1];
    const float* v    = (const float*)d_in[2];
    const int*   mask = (const int*)  d_in[3];
    const float* Wq   = (const float*)d_in[4];
    const float* bq   = (const float*)d_in[5];
    const float* Wkv  = (const float*)d_in[6];
    const float* bkv  = (const float*)d_in[7];
    const float* Wo   = (const float*)d_in[8];
    const float* bo   = (const float*)d_in[9];
    const float* alpha= (const float*)d_in[10];

    char* ws = (char*)d_ws;
    const size_t SZ_F = (size_t)BB * NN * EE * 4;   // 16 MB  (f32 [B*N][E])
    const size_t SZ_H = (size_t)BB * NN * EE * 2;   //  8 MB  (u16 [B*N][E])
    const size_t SZ_W = (size_t)EE * EE * 2;        //  2 MB  (u16 [E][E])
    float*  vp    = (float*)(ws);                 size_t off = SZ_F;
    float*  oatt  = (float*)(ws + off);           off += SZ_F;
    ushort* qp_hi = (ushort*)(ws + off);          off += SZ_H;
    ushort* qp_lo = (ushort*)(ws + off);          off += SZ_H;
    ushort* kp_hi = (ushort*)(ws + off);          off += SZ_H;
    ushort* kp_lo = (ushort*)(ws + off);          off += SZ_H;
    ushort* vT_hi = (ushort*)(ws + off);          off += SZ_H;
    ushort* vT_lo = (ushort*)(ws + off);          off += SZ_H;
    ushort* WqTh  = (ushort*)(ws + off);          off += SZ_W;
    ushort* WqTl  = (ushort*)(ws + off);          off += SZ_W;
    ushort* WkTh  = (ushort*)(ws + off);          off += SZ_W;
    ushort* WkTl  = (ushort*)(ws + off);          off += SZ_W;
    ushort* WoTh  = (ushort*)(ws + off);          off += SZ_W;
    ushort* WoTl  = (ushort*)(ws + off);          off += SZ_W;
    float*  mbuf  = (float*)(ws + off);           off += (size_t)BB * HH * NN * 4;
    float*  lbuf  = (float*)(ws + off);           off += (size_t)BB * HH * NN * 4;
    int*    flag  = (int*)(ws + off);

    float* out_o = (float*)d_out;                  // [B,N,E]
    float* out_w = out_o + (size_t)BB * NN * EE;   // [B,N,N]

    k_zero_flag<<<1, 1, 0, stream>>>(flag);
    k_maskflag<<<1024, 256, 0, stream>>>(mask, flag);

    dim3 gw(EE / 64, EE / 64);
    k_convW<<<gw, 256, 0, stream>>>(Wq,  WqTh, WqTl);
    k_convW<<<gw, 256, 0, stream>>>(Wkv, WkTh, WkTl);
    k_convW<<<gw, 256, 0, stream>>>(Wo,  WoTh, WoTl);

    dim3 gg(EE / 128, (BB * NN) / 128);   // (8, 32)
    k_mgemm<0, 1><<<gg, 256, 0, stream>>>(q, nullptr, nullptr, WqTh, WqTl, bq, SCALE,
                                          nullptr, qp_hi, qp_lo);
    k_mgemm<0, 1><<<gg, 256, 0, stream>>>(k, nullptr, nullptr, WkTh, WkTl, bkv, 1.f,
                                          nullptr, kp_hi, kp_lo);
    k_mgemm<1, 0><<<gg, 256, 0, stream>>>(v, nullptr, nullptr, WkTh, WkTl, bkv, 1.f,
                                          vp, nullptr, nullptr);
    k_transV<<<dim3(NN / 64, EE / 64, BB), 256, 0, stream>>>(vp, vT_hi, vT_lo);

    k_attn<<<dim3(NN / 64, BB * HH), 256, 0, stream>>>(qp_hi, qp_lo, kp_hi, kp_lo,
                                                       vT_hi, vT_lo, mask, flag,
                                                       mbuf, lbuf, oatt);
    k_wsum<<<dim3(NN / 64, NN / 64, BB), 256, 0, stream>>>(qp_hi, qp_lo, kp_hi, kp_lo,
                                                           mask, flag, mbuf, lbuf, out_w);

    k_mgemm<1, 0><<<gg, 256, 0, stream>>>(oatt, vp, alpha, WoTh, WoTl, bo, 1.f,
                                          out_o, nullptr, nullptr);
}

// Round 6
// 572.689 us; speedup vs baseline: 4.6927x; 1.2072x over previous
//
#include <hip/hip_runtime.h>
#include <math.h>

#define BB 2
#define NN 2048
#define EE 1024
#define HH 16
#define DD 64
#define SCALE 0.125f

typedef __attribute__((ext_vector_type(8))) short bf16x8;
typedef __attribute__((ext_vector_type(4))) float f32x4;

#define MFMA16(a,b,c) __builtin_amdgcn_mfma_f32_16x16x32_bf16((a),(b),(c),0,0,0)

__device__ __forceinline__ ushort f2bf(float x){
    unsigned u = __float_as_uint(x);
    return (ushort)((u + 0x7fffu + ((u>>16)&1u)) >> 16);
}
__device__ __forceinline__ float bf2f(ushort h){ return __uint_as_float(((unsigned)h)<<16); }

union U4 { uint4 v; ushort s[8]; };

// async global->LDS, 16B per lane, linear dest (guide §5 / m97 / m173)
__device__ __forceinline__ void gload16(const void* g, void* l) {
    __builtin_amdgcn_global_load_lds(
        (const __attribute__((address_space(1))) unsigned int*)g,
        (__attribute__((address_space(3))) unsigned int*)l, 16, 0, 0);
}

// Swizzle convention for all bf16 operand buffers (qp_hi, kp_hi/lo, vT_hi, P):
// within each 64-aligned 64-col tile, physical_col = col ^ ((row&7)<<3).
// Makes ds_read_b128 frag reads bank-conflict-free after linear gload_lds staging.

// ---------------- tiny init + mask flag ----------------
__global__ void k_zero_flag(int* flag) { *flag = 0; }

__global__ void k_maskflag(const int* __restrict__ mask, int* __restrict__ flag) {
    int tid = blockIdx.x * blockDim.x + threadIdx.x;
    int has = 0;
    const int total = NN * NN;
    for (int i = tid; i < total; i += gridDim.x * blockDim.x)
        has |= (mask[i] == 0);
    if (__any(has) && (threadIdx.x & 63) == 0)
        atomicOr(flag, 1);
}

// ---------------- weight transpose + split: W[K][Nc] -> WT_hi/lo[Nc][K] ----------
__global__ __launch_bounds__(256) void k_convW(const float* __restrict__ W,
                                               ushort* __restrict__ Thi,
                                               ushort* __restrict__ Tlo) {
    __shared__ float T[64][65];
    const int t = threadIdx.x;
    const int n0 = blockIdx.x * 64, k0 = blockIdx.y * 64;
    #pragma unroll
    for (int ch = 0; ch < 4; ch++) {
        int idx = t + ch * 256;
        int r = idx >> 4, c4 = idx & 15;
        float4 g = *(const float4*)&W[(size_t)(k0 + r) * EE + n0 + c4 * 4];
        T[r][c4 * 4 + 0] = g.x; T[r][c4 * 4 + 1] = g.y;
        T[r][c4 * 4 + 2] = g.z; T[r][c4 * 4 + 3] = g.w;
    }
    __syncthreads();
    #pragma unroll
    for (int ch = 0; ch < 4; ch++) {
        int idx = t + ch * 256;
        int nl = idx >> 4, k4 = idx & 15;
        ushort4 h4, l4;
        float x0 = T[k4 * 4 + 0][nl], x1 = T[k4 * 4 + 1][nl];
        float x2 = T[k4 * 4 + 2][nl], x3 = T[k4 * 4 + 3][nl];
        h4.x = f2bf(x0); l4.x = f2bf(x0 - bf2f(h4.x));
        h4.y = f2bf(x1); l4.y = f2bf(x1 - bf2f(h4.y));
        h4.z = f2bf(x2); l4.z = f2bf(x2 - bf2f(h4.z));
        h4.w = f2bf(x3); l4.w = f2bf(x3 - bf2f(h4.w));
        size_t o = (size_t)(n0 + nl) * EE + k0 + k4 * 4;
        *(ushort4*)&Thi[o] = h4;
        *(ushort4*)&Tlo[o] = l4;
    }
}

// ---------------- MFMA GEMM: C = (A [+ alpha*addA]) @ W + bias ----------------
// BM=64, BN=128, BK=32, 256 thr (4 waves 2x2). 2-term: Ah*(Bh+Bl).
// WF32: f32 C.  WHI(+WLO): bf16 hi(/lo) swizzled C*cscale.  WVT: transposed
// swizzled bf16 hi into CvT[B][E][N] (fused transV).
template<int WF32, int WHI, int WLO, int WVT>
__global__ __launch_bounds__(256) void k_mgemm(
    const float* __restrict__ A, const float* __restrict__ addA,
    const float* __restrict__ alphap,
    const ushort* __restrict__ BTh, const ushort* __restrict__ BTl,
    const float* __restrict__ bias, float cscale,
    float* __restrict__ Cf, ushort* __restrict__ Chi, ushort* __restrict__ Clo,
    ushort* __restrict__ CvT)
{
    __shared__ __align__(16) ushort Ah[64 * 32];
    __shared__ __align__(16) ushort Bh[128 * 32];
    __shared__ __align__(16) ushort Bl[128 * 32];
    const int t = threadIdx.x;
    const int m0 = blockIdx.y * 64, n0 = blockIdx.x * 128;
    const int w = t >> 6, l = t & 63;
    const int wm = w >> 1, wn = w & 1;
    const int ln = t & 15, lg = (t >> 4) & 3;
    const int ar = t >> 2, ac = (t & 3) * 8;
    const float alpha = addA ? alphap[0] : 0.f;

    f32x4 acc[2][4];
    #pragma unroll
    for (int mt = 0; mt < 2; mt++)
        #pragma unroll
        for (int nt = 0; nt < 4; nt++) acc[mt][nt] = (f32x4){0.f, 0.f, 0.f, 0.f};

    for (int k0 = 0; k0 < EE; k0 += 32) {
        // A tile -> regs (f32)
        float4 a0 = *(const float4*)&A[(size_t)(m0 + ar) * EE + k0 + ac];
        float4 a1 = *(const float4*)&A[(size_t)(m0 + ar) * EE + k0 + ac + 4];
        if (addA) {
            float4 x0 = *(const float4*)&addA[(size_t)(m0 + ar) * EE + k0 + ac];
            float4 x1 = *(const float4*)&addA[(size_t)(m0 + ar) * EE + k0 + ac + 4];
            a0.x += alpha * x0.x; a0.y += alpha * x0.y; a0.z += alpha * x0.z; a0.w += alpha * x0.w;
            a1.x += alpha * x1.x; a1.y += alpha * x1.y; a1.z += alpha * x1.z; a1.w += alpha * x1.w;
        }
        __syncthreads();   // previous iteration's LDS reads done
        // B hi/lo staging via global_load_lds (linear, 64B rows -> conflict-floor)
        #pragma unroll
        for (int i = 0; i < 2; i++) {
            const int r_ = w * 32 + i * 16 + (l >> 2);
            const int cu = (l & 3) * 8;
            gload16(&BTh[(size_t)(n0 + r_) * EE + k0 + cu], &Bh[r_ * 32 + cu]);
            gload16(&BTl[(size_t)(n0 + r_) * EE + k0 + cu], &Bl[r_ * 32 + cu]);
        }
        // A convert + ds_write
        {
            U4 p;
            const float av[8] = {a0.x, a0.y, a0.z, a0.w, a1.x, a1.y, a1.z, a1.w};
            #pragma unroll
            for (int i = 0; i < 8; i++) p.s[i] = f2bf(av[i]);
            *(uint4*)&Ah[ar * 32 + ac] = p.v;
        }
        __syncthreads();   // drains vmcnt (gload) + lgkm (ds_write)
        bf16x8 af[2], bh8[4], bl8[4];
        #pragma unroll
        for (int mt = 0; mt < 2; mt++)
            af[mt] = *(const bf16x8*)&Ah[(wm * 32 + mt * 16 + ln) * 32 + lg * 8];
        #pragma unroll
        for (int nt = 0; nt < 4; nt++) {
            bh8[nt] = *(const bf16x8*)&Bh[(wn * 64 + nt * 16 + ln) * 32 + lg * 8];
            bl8[nt] = *(const bf16x8*)&Bl[(wn * 64 + nt * 16 + ln) * 32 + lg * 8];
        }
        #pragma unroll
        for (int mt = 0; mt < 2; mt++)
            #pragma unroll
            for (int nt = 0; nt < 4; nt++) {
                acc[mt][nt] = MFMA16(af[mt], bh8[nt], acc[mt][nt]);
                acc[mt][nt] = MFMA16(af[mt], bl8[nt], acc[mt][nt]);
            }
    }
    #pragma unroll
    for (int nt = 0; nt < 4; nt++) {
        const int col = n0 + wn * 64 + nt * 16 + ln;
        const float bv = bias[col];
        #pragma unroll
        for (int mt = 0; mt < 2; mt++)
            #pragma unroll
            for (int j = 0; j < 4; j++) {
                const int row = m0 + wm * 32 + mt * 16 + 4 * lg + j;
                float val = acc[mt][nt][j] + bv;
                if (WF32) Cf[(size_t)row * EE + col] = val;
                if (WHI) {
                    float sv = val * cscale;
                    ushort hh = f2bf(sv);
                    size_t o = (size_t)row * EE + (col ^ ((row & 7) << 3));
                    Chi[o] = hh;
                    if (WLO) Clo[o] = f2bf(sv - bf2f(hh));
                }
                if (WVT) {
                    const int b_ = row >> 11, nn_ = row & (NN - 1);
                    CvT[((size_t)b_ * EE + col) * NN + (nn_ ^ ((col & 7) << 3))] = f2bf(val);
                }
            }
    }
}

// ---------------- MFMA flash attention, QBLK=128, KVBLK=64 ----------------
__global__ __launch_bounds__(256) void k_attn(
    const ushort* __restrict__ qph,
    const ushort* __restrict__ kph, const ushort* __restrict__ kpl,
    const ushort* __restrict__ vTh,
    const int* __restrict__ mask, const int* __restrict__ flag,
    float* __restrict__ mbuf, float* __restrict__ lbuf, float* __restrict__ oatt)
{
    __shared__ __align__(16) ushort Kh[64 * 64], Kl[64 * 64], Vh[64 * 64];
    __shared__ __align__(16) ushort Ps[128 * 64];
    const int t = threadIdx.x;
    const int it = blockIdx.x, bh = blockIdx.y;
    const int b = bh >> 4, h = bh & 15;
    const int i0 = it * 128;
    const int w = t >> 6, l = t & 63;
    const int ln = t & 15, lg = (t >> 4) & 3;
    const int hasmask = *flag;

    // Q frags in registers for the whole kernel (hi only; swizzled storage)
    bf16x8 qh[2][2];
    #pragma unroll
    for (int qi = 0; qi < 2; qi++) {
        const int R = i0 + w * 32 + qi * 16 + ln;
        const size_t ro = (size_t)(b * NN + R) * EE + h * 64;
        #pragma unroll
        for (int ks = 0; ks < 2; ks++)
            qh[qi][ks] = *(const bf16x8*)&qph[ro + ((ks * 32 + lg * 8) ^ ((ln & 7) << 3))];
    }
    float m_[2][4], l_[2][4];
    f32x4 oacc[2][4];
    #pragma unroll
    for (int qi = 0; qi < 2; qi++) {
        #pragma unroll
        for (int r = 0; r < 4; r++) { m_[qi][r] = -INFINITY; l_[qi][r] = 0.f; }
        #pragma unroll
        for (int df = 0; df < 4; df++) oacc[qi][df] = (f32x4){0.f, 0.f, 0.f, 0.f};
    }

    for (int jt = 0; jt < 32; jt++) {
        const int j0 = jt * 64;
        __syncthreads();   // all waves done reading previous K/V
        #pragma unroll
        for (int i = 0; i < 2; i++) {
            const int r_ = w * 16 + i * 8 + (l >> 3);
            const int cu = (l & 7) * 8;
            gload16(&kph[(size_t)(b * NN + j0 + r_) * EE + h * 64 + cu], &Kh[r_ * 64 + cu]);
            gload16(&kpl[(size_t)(b * NN + j0 + r_) * EE + h * 64 + cu], &Kl[r_ * 64 + cu]);
            gload16(&vTh[((size_t)b * EE + h * 64 + r_) * NN + j0 + cu], &Vh[r_ * 64 + cu]);
        }
        __syncthreads();   // staging complete (vmcnt drained)
        // QK^T (2-term: qh*(kh+kl)), K loads hoisted over qi
        f32x4 s[2][4];
        #pragma unroll
        for (int kf = 0; kf < 4; kf++) {
            bf16x8 kh8[2], kl8[2];
            #pragma unroll
            for (int ks = 0; ks < 2; ks++) {
                const int ro = (kf * 16 + ln) * 64 + ((ks * 32 + lg * 8) ^ ((ln & 7) << 3));
                kh8[ks] = *(const bf16x8*)&Kh[ro];
                kl8[ks] = *(const bf16x8*)&Kl[ro];
            }
            #pragma unroll
            for (int qi = 0; qi < 2; qi++) {
                f32x4 sv = (f32x4){0.f, 0.f, 0.f, 0.f};
                #pragma unroll
                for (int ks = 0; ks < 2; ks++) {
                    sv = MFMA16(qh[qi][ks], kh8[ks], sv);
                    sv = MFMA16(qh[qi][ks], kl8[ks], sv);
                }
                s[qi][kf] = sv;
            }
        }
        if (hasmask) {
            #pragma unroll
            for (int qi = 0; qi < 2; qi++)
                #pragma unroll
                for (int kf = 0; kf < 4; kf++)
                    #pragma unroll
                    for (int r = 0; r < 4; r++)
                        if (mask[(size_t)(i0 + w * 32 + qi * 16 + 4 * lg + r) * NN +
                                 j0 + kf * 16 + ln] == 0)
                            s[qi][kf][r] = -INFINITY;
        }
        // online softmax; P -> LDS (bf16, swizzled)
        #pragma unroll
        for (int qi = 0; qi < 2; qi++)
            #pragma unroll
            for (int r = 0; r < 4; r++) {
                float s0 = s[qi][0][r], s1 = s[qi][1][r];
                float s2 = s[qi][2][r], s3 = s[qi][3][r];
                float mx = fmaxf(fmaxf(s0, s1), fmaxf(s2, s3));
                #pragma unroll
                for (int off = 1; off < 16; off <<= 1) mx = fmaxf(mx, __shfl_xor(mx, off));
                float nm = fmaxf(m_[qi][r], mx);
                float scf, psum;
                ushort p0, p1, p2, p3;
                if (nm == -INFINITY) {
                    scf = 1.f; psum = 0.f; p0 = p1 = p2 = p3 = 0;
                } else {
                    scf = __expf(m_[qi][r] - nm);
                    float e0 = __expf(s0 - nm), e1 = __expf(s1 - nm);
                    float e2 = __expf(s2 - nm), e3 = __expf(s3 - nm);
                    p0 = f2bf(e0); p1 = f2bf(e1); p2 = f2bf(e2); p3 = f2bf(e3);
                    psum = e0 + e1 + e2 + e3;
                    #pragma unroll
                    for (int off = 1; off < 16; off <<= 1) psum += __shfl_xor(psum, off);
                }
                l_[qi][r] = l_[qi][r] * scf + psum;
                m_[qi][r] = nm;
                #pragma unroll
                for (int df = 0; df < 4; df++) oacc[qi][df][r] *= scf;
                const int prow = w * 32 + qi * 16 + 4 * lg + r;
                const int sw = ((4 * lg + r) & 7) << 3;
                Ps[prow * 64 + ((0  + ln) ^ sw)] = p0;
                Ps[prow * 64 + ((16 + ln) ^ sw)] = p1;
                Ps[prow * 64 + ((32 + ln) ^ sw)] = p2;
                Ps[prow * 64 + ((48 + ln) ^ sw)] = p3;
            }
        __syncthreads();   // (safety; P traffic is intra-wave)
        // PV (1-term, V hi), V loads hoisted over qi
        #pragma unroll
        for (int ks = 0; ks < 2; ks++) {
            bf16x8 v8[4];
            #pragma unroll
            for (int df = 0; df < 4; df++)
                v8[df] = *(const bf16x8*)&Vh[(df * 16 + ln) * 64 +
                                             ((ks * 32 + lg * 8) ^ ((ln & 7) << 3))];
            #pragma unroll
            for (int qi = 0; qi < 2; qi++) {
                bf16x8 pf = *(const bf16x8*)&Ps[(w * 32 + qi * 16 + ln) * 64 +
                                                ((ks * 32 + lg * 8) ^ ((ln & 7) << 3))];
                #pragma unroll
                for (int df = 0; df < 4; df++)
                    oacc[qi][df] = MFMA16(pf, v8[df], oacc[qi][df]);
            }
        }
    }
    #pragma unroll
    for (int qi = 0; qi < 2; qi++)
        #pragma unroll
        for (int r = 0; r < 4; r++) {
            const int q = i0 + w * 32 + qi * 16 + 4 * lg + r;
            float li = 1.f / l_[qi][r];
            #pragma unroll
            for (int df = 0; df < 4; df++)
                oatt[(size_t)(b * NN + q) * EE + h * 64 + df * 16 + ln] = oacc[qi][df][r] * li;
            if (ln == 0) {
                mbuf[(size_t)bh * NN + q] = m_[qi][r];
                lbuf[(size_t)bh * NN + q] = li;
            }
        }
}

// ---------------- wsum[b,i,j] = sum_h exp(s - m) * linv ----------------
__global__ __launch_bounds__(256) void k_wsum(
    const ushort* __restrict__ qph,
    const ushort* __restrict__ kph, const ushort* __restrict__ kpl,
    const int* __restrict__ mask, const int* __restrict__ flag,
    const float* __restrict__ mbuf, const float* __restrict__ lbuf,
    float* __restrict__ wsum)
{
    __shared__ __align__(16) ushort Qh[64 * 64], Kh[64 * 64], Kl[64 * 64];
    __shared__ float Ms[16 * 64], Ls[16 * 64];
    const int t = threadIdx.x;
    const int jt = blockIdx.x, it = blockIdx.y, b = blockIdx.z;
    const int i0 = it * 64, j0 = jt * 64;
    const int w = t >> 6, l = t & 63;
    const int ln = t & 15, lg = (t >> 4) & 3;
    const int hasmask = *flag;

    #pragma unroll
    for (int ch = 0; ch < 4; ch++) {
        const int idx = t + ch * 256;
        Ms[idx] = mbuf[((size_t)b * HH + (idx >> 6)) * NN + i0 + (idx & 63)];
        Ls[idx] = lbuf[((size_t)b * HH + (idx >> 6)) * NN + i0 + (idx & 63)];
    }
    unsigned mbits = 0;
    if (hasmask) {
        #pragma unroll
        for (int kf = 0; kf < 4; kf++)
            #pragma unroll
            for (int r = 0; r < 4; r++)
                if (mask[(size_t)(i0 + w * 16 + 4 * lg + r) * NN + j0 + kf * 16 + ln] == 0)
                    mbits |= 1u << (kf * 4 + r);
    }
    float wacc[4][4] = {};
    for (int h = 0; h < HH; h++) {
        __syncthreads();
        #pragma unroll
        for (int i = 0; i < 2; i++) {
            const int r_ = w * 16 + i * 8 + (l >> 3);
            const int cu = (l & 7) * 8;
            gload16(&qph[(size_t)(b * NN + i0 + r_) * EE + h * 64 + cu], &Qh[r_ * 64 + cu]);
            gload16(&kph[(size_t)(b * NN + j0 + r_) * EE + h * 64 + cu], &Kh[r_ * 64 + cu]);
            gload16(&kpl[(size_t)(b * NN + j0 + r_) * EE + h * 64 + cu], &Kl[r_ * 64 + cu]);
        }
        __syncthreads();
        bf16x8 q8[2];
        #pragma unroll
        for (int ks = 0; ks < 2; ks++)
            q8[ks] = *(const bf16x8*)&Qh[(w * 16 + ln) * 64 +
                                         ((ks * 32 + lg * 8) ^ ((ln & 7) << 3))];
        #pragma unroll
        for (int kf = 0; kf < 4; kf++) {
            f32x4 sv = (f32x4){0.f, 0.f, 0.f, 0.f};
            #pragma unroll
            for (int ks = 0; ks < 2; ks++) {
                const int ro = (kf * 16 + ln) * 64 + ((ks * 32 + lg * 8) ^ ((ln & 7) << 3));
                bf16x8 kh8 = *(const bf16x8*)&Kh[ro];
                bf16x8 kl8 = *(const bf16x8*)&Kl[ro];
                sv = MFMA16(q8[ks], kh8, sv);
                sv = MFMA16(q8[ks], kl8, sv);
            }
            #pragma unroll
            for (int r = 0; r < 4; r++)
                if (!((mbits >> (kf * 4 + r)) & 1u)) {
                    const int qq = w * 16 + 4 * lg + r;
                    wacc[kf][r] += __expf(sv[r] - Ms[h * 64 + qq]) * Ls[h * 64 + qq];
                }
        }
    }
    #pragma unroll
    for (int kf = 0; kf < 4; kf++)
        #pragma unroll
        for (int r = 0; r < 4; r++)
            wsum[(size_t)b * NN * NN +
                 (size_t)(i0 + w * 16 + 4 * lg + r) * NN + j0 + kf * 16 + ln] = wacc[kf][r];
}

// ---------------- launch ----------------
extern "C" void kernel_launch(void* const* d_in, const int* in_sizes, int n_in,
                              void* d_out, int out_size, void* d_ws, size_t ws_size,
                              hipStream_t stream) {
    const float* q    = (const float*)d_in[0];
    const float* k    = (const float*)d_in[1];
    const float* v    = (const float*)d_in[2];
    const int*   mask = (const int*)  d_in[3];
    const float* Wq   = (const float*)d_in[4];
    const float* bq   = (const float*)d_in[5];
    const float* Wkv  = (const float*)d_in[6];
    const float* bkv  = (const float*)d_in[7];
    const float* Wo   = (const float*)d_in[8];
    const float* bo   = (const float*)d_in[9];
    const float* alpha= (const float*)d_in[10];

    char* ws = (char*)d_ws;
    const size_t SZ_F = (size_t)BB * NN * EE * 4;   // 16 MB
    const size_t SZ_H = (size_t)BB * NN * EE * 2;   //  8 MB
    const size_t SZ_W = (size_t)EE * EE * 2;        //  2 MB
    size_t off = 0;
    float*  vp    = (float*)(ws + off);           off += SZ_F;
    float*  oatt  = (float*)(ws + off);           off += SZ_F;
    ushort* qp_hi = (ushort*)(ws + off);          off += SZ_H;
    ushort* kp_hi = (ushort*)(ws + off);          off += SZ_H;
    ushort* kp_lo = (ushort*)(ws + off);          off += SZ_H;
    ushort* vT_hi = (ushort*)(ws + off);          off += SZ_H;
    ushort* WqTh  = (ushort*)(ws + off);          off += SZ_W;
    ushort* WqTl  = (ushort*)(ws + off);          off += SZ_W;
    ushort* WkTh  = (ushort*)(ws + off);          off += SZ_W;
    ushort* WkTl  = (ushort*)(ws + off);          off += SZ_W;
    ushort* WoTh  = (ushort*)(ws + off);          off += SZ_W;
    ushort* WoTl  = (ushort*)(ws + off);          off += SZ_W;
    float*  mbuf  = (float*)(ws + off);           off += (size_t)BB * HH * NN * 4;
    float*  lbuf  = (float*)(ws + off);           off += (size_t)BB * HH * NN * 4;
    int*    flag  = (int*)(ws + off);

    float* out_o = (float*)d_out;                  // [B,N,E]
    float* out_w = out_o + (size_t)BB * NN * EE;   // [B,N,N]

    k_zero_flag<<<1, 1, 0, stream>>>(flag);
    k_maskflag<<<1024, 256, 0, stream>>>(mask, flag);

    dim3 gw(EE / 64, EE / 64);
    k_convW<<<gw, 256, 0, stream>>>(Wq,  WqTh, WqTl);
    k_convW<<<gw, 256, 0, stream>>>(Wkv, WkTh, WkTl);
    k_convW<<<gw, 256, 0, stream>>>(Wo,  WoTh, WoTl);

    dim3 gg(EE / 128, (BB * NN) / 64);   // (8, 64) = 512 blocks
    // qp: bf16 hi, folded SCALE, swizzled
    k_mgemm<0,1,0,0><<<gg, 256, 0, stream>>>(q, nullptr, nullptr, WqTh, WqTl, bq, SCALE,
                                             nullptr, qp_hi, nullptr, nullptr);
    // kp: bf16 hi+lo, swizzled
    k_mgemm<0,1,1,0><<<gg, 256, 0, stream>>>(k, nullptr, nullptr, WkTh, WkTl, bkv, 1.f,
                                             nullptr, kp_hi, kp_lo, nullptr);
    // vp: f32 + fused transposed bf16 hi (vT)
    k_mgemm<1,0,0,1><<<gg, 256, 0, stream>>>(v, nullptr, nullptr, WkTh, WkTl, bkv, 1.f,
                                             vp, nullptr, nullptr, vT_hi);

    k_attn<<<dim3(NN / 128, BB * HH), 256, 0, stream>>>(qp_hi, kp_hi, kp_lo, vT_hi,
                                                        mask, flag, mbuf, lbuf, oatt);
    k_wsum<<<dim3(NN / 64, NN / 64, BB), 256, 0, stream>>>(qp_hi, kp_hi, kp_lo,
                                                           mask, flag, mbuf, lbuf, out_w);

    // out = (oatt + alpha*vp) @ Wo + bo
    k_mgemm<1,0,0,0><<<gg, 256, 0, stream>>>(oatt, vp, alpha, WoTh, WoTl, bo, 1.f,
                                             out_o, nullptr, nullptr, nullptr);
}

// Round 8
// 425.089 us; speedup vs baseline: 6.3222x; 1.3472x over previous
//
#include <hip/hip_runtime.h>
#include <math.h>

#define BB 2
#define NN 2048
#define EE 1024
#define HH 16
#define DD 64
#define SCALE 0.125f

typedef __attribute__((ext_vector_type(8))) short bf16x8;
typedef __attribute__((ext_vector_type(4))) float f32x4;

#define MFMA16(a,b,c) __builtin_amdgcn_mfma_f32_16x16x32_bf16((a),(b),(c),0,0,0)

__device__ __forceinline__ ushort f2bf(float x){
    unsigned u = __float_as_uint(x);
    return (ushort)((u + 0x7fffu + ((u>>16)&1u)) >> 16);
}
__device__ __forceinline__ float bf2f(ushort h){ return __uint_as_float(((unsigned)h)<<16); }

union U4 { uint4 v; ushort s[8]; };

// async global->LDS, 16B/lane, linear dest (dest offsets == base + lane*16)
__device__ __forceinline__ void gload16(const void* g, void* l) {
    __builtin_amdgcn_global_load_lds(
        (const __attribute__((address_space(1))) unsigned int*)g,
        (__attribute__((address_space(3))) unsigned int*)l, 16, 0, 0);
}

// Swizzle convention for all bf16 operand buffers (qp_hi, kp_hi/lo, vT_hi, P,
// and the pre-converted weights): within each 64-aligned 64-col tile,
// physical_col = col ^ ((row&7)<<3). Linear gload_lds + XOR on ds_read = conflict-free.

// ---------------- tiny init + mask flag ----------------
__global__ void k_zero_flag(int* flag) { *flag = 0; }

__global__ void k_maskflag(const int* __restrict__ mask, int* __restrict__ flag) {
    int tid = blockIdx.x * blockDim.x + threadIdx.x;
    int has = 0;
    const int total = NN * NN;
    for (int i = tid; i < total; i += gridDim.x * blockDim.x)
        has |= (mask[i] == 0);
    if (__any(has) && (threadIdx.x & 63) == 0)
        atomicOr(flag, 1);
}

// ---------------- weight transpose + split: W[K][Nc] -> WT_hi/lo[Nc][K], swizzled ----
__global__ __launch_bounds__(256) void k_convW(const float* __restrict__ W,
                                               ushort* __restrict__ Thi,
                                               ushort* __restrict__ Tlo) {
    __shared__ float T[64][65];
    const int t = threadIdx.x;
    const int n0 = blockIdx.x * 64, k0 = blockIdx.y * 64;
    #pragma unroll
    for (int ch = 0; ch < 4; ch++) {
        int idx = t + ch * 256;
        int r = idx >> 4, c4 = idx & 15;
        float4 g = *(const float4*)&W[(size_t)(k0 + r) * EE + n0 + c4 * 4];
        T[r][c4 * 4 + 0] = g.x; T[r][c4 * 4 + 1] = g.y;
        T[r][c4 * 4 + 2] = g.z; T[r][c4 * 4 + 3] = g.w;
    }
    __syncthreads();
    #pragma unroll
    for (int ch = 0; ch < 4; ch++) {
        int idx = t + ch * 256;
        int nl = idx >> 4, k4 = idx & 15;
        ushort4 h4, l4;
        float x0 = T[k4 * 4 + 0][nl], x1 = T[k4 * 4 + 1][nl];
        float x2 = T[k4 * 4 + 2][nl], x3 = T[k4 * 4 + 3][nl];
        h4.x = f2bf(x0); l4.x = f2bf(x0 - bf2f(h4.x));
        h4.y = f2bf(x1); l4.y = f2bf(x1 - bf2f(h4.y));
        h4.z = f2bf(x2); l4.z = f2bf(x2 - bf2f(h4.z));
        h4.w = f2bf(x3); l4.w = f2bf(x3 - bf2f(h4.w));
        // swizzled store: col = k4*4 -> chunk (k4>>1), inner (k4&1)*4
        int phys = (((k4 >> 1) ^ (nl & 7)) << 3) + ((k4 & 1) << 2);
        size_t o = (size_t)(n0 + nl) * EE + k0 + phys;
        *(ushort4*)&Thi[o] = h4;
        *(ushort4*)&Tlo[o] = l4;
    }
}

// ---------------- MFMA GEMM: C = A @ W + bias ----------------
// BM=64, BN=128, BK=64, 256 thr (4 waves 2x2). 2-term: Ah*(Bh+Bl).
// A f32 row-major (converted in-loop); B pre-swizzled bf16 hi/lo [Nc][K].
template<int WF32, int WHI, int WLO, int WVT>
__global__ __launch_bounds__(256) void k_mgemm(
    const float* __restrict__ A,
    const ushort* __restrict__ BTh, const ushort* __restrict__ BTl,
    const float* __restrict__ bias, float cscale,
    float* __restrict__ Cf, ushort* __restrict__ Chi, ushort* __restrict__ Clo,
    ushort* __restrict__ CvT)
{
    __shared__ __align__(16) ushort Ah[64 * 64];    //  8 KB
    __shared__ __align__(16) ushort Bh[128 * 64];   // 16 KB
    __shared__ __align__(16) ushort Bl[128 * 64];   // 16 KB
    const int t = threadIdx.x;
    const int m0 = blockIdx.y * 64, n0 = blockIdx.x * 128;
    const int w = t >> 6, l = t & 63;
    const int wm = w >> 1, wn = w & 1;
    const int ln = t & 15, lg = (t >> 4) & 3;
    const int ar = t >> 2, acu = (t & 3) * 16;      // A staging: row, 16-col chunk

    f32x4 acc[2][4];
    #pragma unroll
    for (int mt = 0; mt < 2; mt++)
        #pragma unroll
        for (int nt = 0; nt < 4; nt++) acc[mt][nt] = (f32x4){0.f, 0.f, 0.f, 0.f};

    for (int k0 = 0; k0 < EE; k0 += 64) {
        // A tile -> regs (f32)
        float4 a[4];
        #pragma unroll
        for (int i = 0; i < 4; i++)
            a[i] = *(const float4*)&A[(size_t)(m0 + ar) * EE + k0 + acu + i * 4];
        __syncthreads();   // previous iteration's LDS reads done
        // B hi/lo staging via global_load_lds (linear dest; source pre-swizzled)
        #pragma unroll
        for (int i = 0; i < 4; i++) {
            const int r_ = w * 32 + i * 8 + (l >> 3);
            const int cu = (l & 7) * 8;
            gload16(&BTh[(size_t)(n0 + r_) * EE + k0 + cu], &Bh[r_ * 64 + cu]);
            gload16(&BTl[(size_t)(n0 + r_) * EE + k0 + cu], &Bl[r_ * 64 + cu]);
        }
        // A convert + swizzled ds_write (two b128 at XOR'd chunk pair)
        {
            U4 p0, p1;
            const float* af_ = (const float*)a;
            #pragma unroll
            for (int i = 0; i < 8; i++) p0.s[i] = f2bf(af_[i]);
            #pragma unroll
            for (int i = 0; i < 8; i++) p1.s[i] = f2bf(af_[8 + i]);
            const int c0 = acu >> 3;   // even chunk index
            *(uint4*)&Ah[ar * 64 + (((c0    ) ^ (ar & 7)) << 3)] = p0.v;
            *(uint4*)&Ah[ar * 64 + (((c0 + 1) ^ (ar & 7)) << 3)] = p1.v;
        }
        __syncthreads();   // drains vmcnt (gload) + lgkm (ds_write)
        bf16x8 af[2][2], bh8[4][2], bl8[4][2];
        #pragma unroll
        for (int mt = 0; mt < 2; mt++) {
            const int row = wm * 32 + mt * 16 + ln;
            #pragma unroll
            for (int ks = 0; ks < 2; ks++)
                af[mt][ks] = *(const bf16x8*)&Ah[row * 64 + ((ks * 32 + lg * 8) ^ ((ln & 7) << 3))];
        }
        #pragma unroll
        for (int nt = 0; nt < 4; nt++) {
            const int row = wn * 64 + nt * 16 + ln;
            #pragma unroll
            for (int ks = 0; ks < 2; ks++) {
                const int ro = row * 64 + ((ks * 32 + lg * 8) ^ ((ln & 7) << 3));
                bh8[nt][ks] = *(const bf16x8*)&Bh[ro];
                bl8[nt][ks] = *(const bf16x8*)&Bl[ro];
            }
        }
        #pragma unroll
        for (int ks = 0; ks < 2; ks++)
            #pragma unroll
            for (int mt = 0; mt < 2; mt++)
                #pragma unroll
                for (int nt = 0; nt < 4; nt++) {
                    acc[mt][nt] = MFMA16(af[mt][ks], bh8[nt][ks], acc[mt][nt]);
                    acc[mt][nt] = MFMA16(af[mt][ks], bl8[nt][ks], acc[mt][nt]);
                }
    }
    #pragma unroll
    for (int nt = 0; nt < 4; nt++) {
        const int col = n0 + wn * 64 + nt * 16 + ln;
        const float bv = bias[col];
        #pragma unroll
        for (int mt = 0; mt < 2; mt++)
            #pragma unroll
            for (int j = 0; j < 4; j++) {
                const int row = m0 + wm * 32 + mt * 16 + 4 * lg + j;
                float val = acc[mt][nt][j] + bv;
                if (WF32) Cf[(size_t)row * EE + col] = val;
                if (WHI) {
                    float sv = val * cscale;
                    ushort hh = f2bf(sv);
                    size_t o = (size_t)row * EE + (col ^ ((row & 7) << 3));
                    Chi[o] = hh;
                    if (WLO) Clo[o] = f2bf(sv - bf2f(hh));
                }
                if (WVT) {
                    const int b_ = row >> 11, nn_ = row & (NN - 1);
                    CvT[((size_t)b_ * EE + col) * NN + (nn_ ^ ((col & 7) << 3))] = f2bf(val);
                }
            }
    }
}

// ---------------- MFMA flash attention, QBLK=128, KVBLK=64 ----------------
// defer-max softmax (THR=8) + l via ones-column MFMA; fuses alpha*vp into oatt.
__global__ __launch_bounds__(256) void k_attn(
    const ushort* __restrict__ qph,
    const ushort* __restrict__ kph, const ushort* __restrict__ kpl,
    const ushort* __restrict__ vTh,
    const float* __restrict__ vp, const float* __restrict__ alphap,
    const int* __restrict__ mask, const int* __restrict__ flag,
    float* __restrict__ mbuf, float* __restrict__ lbuf, float* __restrict__ oatt)
{
    __shared__ __align__(16) ushort Kh[64 * 64], Kl[64 * 64], Vh[64 * 64];
    __shared__ __align__(16) ushort Ps[128 * 64];
    const int t = threadIdx.x;
    // XCD-chunk swizzle: XCD x (= bid%8) owns bh in [4x, 4x+4)
    const int bid = blockIdx.x;
    const int s_ = bid >> 3;
    const int bh = ((bid & 7) << 2) | (s_ >> 4);
    const int it = s_ & 15;
    const int b = bh >> 4, h = bh & 15;
    const int i0 = it * 128;
    const int w = t >> 6, l = t & 63;
    const int ln = t & 15, lg = (t >> 4) & 3;
    const int hasmask = *flag;
    const float alpha = alphap[0];

    // ones B-fragment for the l-accumulator column (col 0 only)
    bf16x8 vone;
    {
        short o1 = (ln == 0) ? (short)0x3F80 : (short)0;
        vone = (bf16x8){o1, o1, o1, o1, o1, o1, o1, o1};
    }

    // Q frags in registers (hi only; swizzled storage)
    bf16x8 qh[2][2];
    #pragma unroll
    for (int qi = 0; qi < 2; qi++) {
        const int R = i0 + w * 32 + qi * 16 + ln;
        const size_t ro = (size_t)(b * NN + R) * EE + h * 64;
        #pragma unroll
        for (int ks = 0; ks < 2; ks++)
            qh[qi][ks] = *(const bf16x8*)&qph[ro + ((ks * 32 + lg * 8) ^ ((ln & 7) << 3))];
    }
    float m_[2][4];
    f32x4 lacc[2];
    f32x4 oacc[2][4];
    #pragma unroll
    for (int qi = 0; qi < 2; qi++) {
        #pragma unroll
        for (int r = 0; r < 4; r++) m_[qi][r] = -INFINITY;
        lacc[qi] = (f32x4){0.f, 0.f, 0.f, 0.f};
        #pragma unroll
        for (int df = 0; df < 4; df++) oacc[qi][df] = (f32x4){0.f, 0.f, 0.f, 0.f};
    }

    for (int jt = 0; jt < 32; jt++) {
        const int j0 = jt * 64;
        __syncthreads();   // all waves done reading previous K/V
        #pragma unroll
        for (int i = 0; i < 2; i++) {
            const int r_ = w * 16 + i * 8 + (l >> 3);
            const int cu = (l & 7) * 8;
            gload16(&kph[(size_t)(b * NN + j0 + r_) * EE + h * 64 + cu], &Kh[r_ * 64 + cu]);
            gload16(&kpl[(size_t)(b * NN + j0 + r_) * EE + h * 64 + cu], &Kl[r_ * 64 + cu]);
            gload16(&vTh[((size_t)b * EE + h * 64 + r_) * NN + j0 + cu], &Vh[r_ * 64 + cu]);
        }
        __syncthreads();   // staging complete
        // QK^T (2-term)
        f32x4 s[2][4];
        #pragma unroll
        for (int kf = 0; kf < 4; kf++) {
            bf16x8 kh8[2], kl8[2];
            #pragma unroll
            for (int ks = 0; ks < 2; ks++) {
                const int ro = (kf * 16 + ln) * 64 + ((ks * 32 + lg * 8) ^ ((ln & 7) << 3));
                kh8[ks] = *(const bf16x8*)&Kh[ro];
                kl8[ks] = *(const bf16x8*)&Kl[ro];
            }
            #pragma unroll
            for (int qi = 0; qi < 2; qi++) {
                f32x4 sv = (f32x4){0.f, 0.f, 0.f, 0.f};
                #pragma unroll
                for (int ks = 0; ks < 2; ks++) {
                    sv = MFMA16(qh[qi][ks], kh8[ks], sv);
                    sv = MFMA16(qh[qi][ks], kl8[ks], sv);
                }
                s[qi][kf] = sv;
            }
        }
        if (hasmask) {
            #pragma unroll
            for (int qi = 0; qi < 2; qi++)
                #pragma unroll
                for (int kf = 0; kf < 4; kf++)
                    #pragma unroll
                    for (int r = 0; r < 4; r++)
                        if (mask[(size_t)(i0 + w * 32 + qi * 16 + 4 * lg + r) * NN +
                                 j0 + kf * 16 + ln] == 0)
                            s[qi][kf][r] = -INFINITY;
        }
        // defer-max softmax
        #pragma unroll
        for (int qi = 0; qi < 2; qi++) {
            float pmax[4];
            #pragma unroll
            for (int r = 0; r < 4; r++)
                pmax[r] = fmaxf(fmaxf(s[qi][0][r], s[qi][1][r]),
                                fmaxf(s[qi][2][r], s[qi][3][r]));
            bool bad = false;
            #pragma unroll
            for (int r = 0; r < 4; r++)
                bad = bad || (pmax[r] > m_[qi][r] + 8.f) || (m_[qi][r] == -INFINITY);
            if (__any(bad)) {
                // rare/exact path: full reduce + rescale
                #pragma unroll
                for (int r = 0; r < 4; r++) {
                    float mx = pmax[r];
                    #pragma unroll
                    for (int off = 1; off < 16; off <<= 1) mx = fmaxf(mx, __shfl_xor(mx, off));
                    float nm = fmaxf(m_[qi][r], mx);
                    float scf;
                    ushort p0, p1, p2, p3;
                    if (nm == -INFINITY) {
                        scf = 1.f; p0 = p1 = p2 = p3 = 0;
                    } else {
                        scf = __expf(m_[qi][r] - nm);
                        p0 = f2bf(__expf(s[qi][0][r] - nm));
                        p1 = f2bf(__expf(s[qi][1][r] - nm));
                        p2 = f2bf(__expf(s[qi][2][r] - nm));
                        p3 = f2bf(__expf(s[qi][3][r] - nm));
                    }
                    m_[qi][r] = nm;
                    lacc[qi][r] *= scf;
                    #pragma unroll
                    for (int df = 0; df < 4; df++) oacc[qi][df][r] *= scf;
                    const int prow = (w * 32 + qi * 16 + 4 * lg + r) * 64;
                    const int sw = ((4 * lg + r) & 7) << 3;
                    Ps[prow + ((0  + ln) ^ sw)] = p0;
                    Ps[prow + ((16 + ln) ^ sw)] = p1;
                    Ps[prow + ((32 + ln) ^ sw)] = p2;
                    Ps[prow + ((48 + ln) ^ sw)] = p3;
                }
            } else {
                // fast path: m fixed, p = exp(s - m) <= e^8, no rescale, no shuffles
                #pragma unroll
                for (int r = 0; r < 4; r++) {
                    const float mi = m_[qi][r];
                    ushort p0 = f2bf(__expf(s[qi][0][r] - mi));
                    ushort p1 = f2bf(__expf(s[qi][1][r] - mi));
                    ushort p2 = f2bf(__expf(s[qi][2][r] - mi));
                    ushort p3 = f2bf(__expf(s[qi][3][r] - mi));
                    const int prow = (w * 32 + qi * 16 + 4 * lg + r) * 64;
                    const int sw = ((4 * lg + r) & 7) << 3;
                    Ps[prow + ((0  + ln) ^ sw)] = p0;
                    Ps[prow + ((16 + ln) ^ sw)] = p1;
                    Ps[prow + ((32 + ln) ^ sw)] = p2;
                    Ps[prow + ((48 + ln) ^ sw)] = p3;
                }
            }
        }
        // PV (1-term, V hi) + l via ones-column; P traffic is intra-wave (no barrier)
        #pragma unroll
        for (int ks = 0; ks < 2; ks++) {
            bf16x8 v8[4];
            #pragma unroll
            for (int df = 0; df < 4; df++)
                v8[df] = *(const bf16x8*)&Vh[(df * 16 + ln) * 64 +
                                             ((ks * 32 + lg * 8) ^ ((ln & 7) << 3))];
            #pragma unroll
            for (int qi = 0; qi < 2; qi++) {
                bf16x8 pf = *(const bf16x8*)&Ps[(w * 32 + qi * 16 + ln) * 64 +
                                                ((ks * 32 + lg * 8) ^ ((ln & 7) << 3))];
                lacc[qi] = MFMA16(pf, vone, lacc[qi]);
                #pragma unroll
                for (int df = 0; df < 4; df++)
                    oacc[qi][df] = MFMA16(pf, v8[df], oacc[qi][df]);
            }
        }
    }
    #pragma unroll
    for (int qi = 0; qi < 2; qi++)
        #pragma unroll
        for (int r = 0; r < 4; r++) {
            const float lsum = __shfl(lacc[qi][r], t & 48);   // col 0 holder of this lg
            const float li = 1.f / lsum;
            const int q = i0 + w * 32 + qi * 16 + 4 * lg + r;
            #pragma unroll
            for (int df = 0; df < 4; df++) {
                const size_t o = (size_t)(b * NN + q) * EE + h * 64 + df * 16 + ln;
                oatt[o] = oacc[qi][df][r] * li + alpha * vp[o];
            }
            if (ln == 0) {
                mbuf[(size_t)bh * NN + q] = m_[qi][r];
                lbuf[(size_t)bh * NN + q] = li;
            }
        }
}

// ---------------- wsum[b,i,j] = sum_h exp(s - m) * linv ----------------
__global__ __launch_bounds__(256) void k_wsum(
    const ushort* __restrict__ qph,
    const ushort* __restrict__ kph, const ushort* __restrict__ kpl,
    const int* __restrict__ mask, const int* __restrict__ flag,
    const float* __restrict__ mbuf, const float* __restrict__ lbuf,
    float* __restrict__ wsum)
{
    __shared__ __align__(16) ushort Qh[64 * 64], Kh[64 * 64], Kl[64 * 64];
    __shared__ float Ms[16 * 64], Ls[16 * 64];
    const int t = threadIdx.x;
    // XCD-chunk swizzle: XCD x owns jt in [4x, 4x+4) (per batch)
    const int bid = blockIdx.x;
    const int b = bid >> 10;
    const int rr = bid & 1023;
    const int s_ = rr >> 3;
    const int jt = ((rr & 7) << 2) | (s_ >> 5);
    const int it = s_ & 31;
    const int i0 = it * 64, j0 = jt * 64;
    const int w = t >> 6, l = t & 63;
    const int ln = t & 15, lg = (t >> 4) & 3;
    const int hasmask = *flag;

    #pragma unroll
    for (int ch = 0; ch < 4; ch++) {
        const int idx = t + ch * 256;
        Ms[idx] = mbuf[((size_t)b * HH + (idx >> 6)) * NN + i0 + (idx & 63)];
        Ls[idx] = lbuf[((size_t)b * HH + (idx >> 6)) * NN + i0 + (idx & 63)];
    }
    unsigned mbits = 0;
    if (hasmask) {
        #pragma unroll
        for (int kf = 0; kf < 4; kf++)
            #pragma unroll
            for (int r = 0; r < 4; r++)
                if (mask[(size_t)(i0 + w * 16 + 4 * lg + r) * NN + j0 + kf * 16 + ln] == 0)
                    mbits |= 1u << (kf * 4 + r);
    }
    float wacc[4][4] = {};
    for (int h = 0; h < HH; h++) {
        __syncthreads();
        #pragma unroll
        for (int i = 0; i < 2; i++) {
            const int r_ = w * 16 + i * 8 + (l >> 3);
            const int cu = (l & 7) * 8;
            gload16(&qph[(size_t)(b * NN + i0 + r_) * EE + h * 64 + cu], &Qh[r_ * 64 + cu]);
            gload16(&kph[(size_t)(b * NN + j0 + r_) * EE + h * 64 + cu], &Kh[r_ * 64 + cu]);
            gload16(&kpl[(size_t)(b * NN + j0 + r_) * EE + h * 64 + cu], &Kl[r_ * 64 + cu]);
        }
        __syncthreads();
        bf16x8 q8[2];
        #pragma unroll
        for (int ks = 0; ks < 2; ks++)
            q8[ks] = *(const bf16x8*)&Qh[(w * 16 + ln) * 64 +
                                         ((ks * 32 + lg * 8) ^ ((ln & 7) << 3))];
        #pragma unroll
        for (int kf = 0; kf < 4; kf++) {
            f32x4 sv = (f32x4){0.f, 0.f, 0.f, 0.f};
            #pragma unroll
            for (int ks = 0; ks < 2; ks++) {
                const int ro = (kf * 16 + ln) * 64 + ((ks * 32 + lg * 8) ^ ((ln & 7) << 3));
                bf16x8 kh8 = *(const bf16x8*)&Kh[ro];
                bf16x8 kl8 = *(const bf16x8*)&Kl[ro];
                sv = MFMA16(q8[ks], kh8, sv);
                sv = MFMA16(q8[ks], kl8, sv);
            }
            #pragma unroll
            for (int r = 0; r < 4; r++)
                if (!((mbits >> (kf * 4 + r)) & 1u)) {
                    const int qq = w * 16 + 4 * lg + r;
                    wacc[kf][r] += __expf(sv[r] - Ms[h * 64 + qq]) * Ls[h * 64 + qq];
                }
        }
    }
    #pragma unroll
    for (int kf = 0; kf < 4; kf++)
        #pragma unroll
        for (int r = 0; r < 4; r++)
            wsum[(size_t)b * NN * NN +
                 (size_t)(i0 + w * 16 + 4 * lg + r) * NN + j0 + kf * 16 + ln] = wacc[kf][r];
}

// ---------------- launch ----------------
extern "C" void kernel_launch(void* const* d_in, const int* in_sizes, int n_in,
                              void* d_out, int out_size, void* d_ws, size_t ws_size,
                              hipStream_t stream) {
    const float* q    = (const float*)d_in[0];
    const float* k    = (const float*)d_in[1];
    const float* v    = (const float*)d_in[2];
    const int*   mask = (const int*)  d_in[3];
    const float* Wq   = (const float*)d_in[4];
    const float* bq   = (const float*)d_in[5];
    const float* Wkv  = (const float*)d_in[6];
    const float* bkv  = (const float*)d_in[7];
    const float* Wo   = (const float*)d_in[8];
    const float* bo   = (const float*)d_in[9];
    const float* alpha= (const float*)d_in[10];

    char* ws = (char*)d_ws;
    const size_t SZ_F = (size_t)BB * NN * EE * 4;   // 16 MB
    const size_t SZ_H = (size_t)BB * NN * EE * 2;   //  8 MB
    const size_t SZ_W = (size_t)EE * EE * 2;        //  2 MB
    size_t off = 0;
    float*  vp    = (float*)(ws + off);           off += SZ_F;
    float*  oatt  = (float*)(ws + off);           off += SZ_F;
    ushort* qp_hi = (ushort*)(ws + off);          off += SZ_H;
    ushort* kp_hi = (ushort*)(ws + off);          off += SZ_H;
    ushort* kp_lo = (ushort*)(ws + off);          off += SZ_H;
    ushort* vT_hi = (ushort*)(ws + off);          off += SZ_H;
    ushort* WqTh  = (ushort*)(ws + off);          off += SZ_W;
    ushort* WqTl  = (ushort*)(ws + off);          off += SZ_W;
    ushort* WkTh  = (ushort*)(ws + off);          off += SZ_W;
    ushort* WkTl  = (ushort*)(ws + off);          off += SZ_W;
    ushort* WoTh  = (ushort*)(ws + off);          off += SZ_W;
    ushort* WoTl  = (ushort*)(ws + off);          off += SZ_W;
    float*  mbuf  = (float*)(ws + off);           off += (size_t)BB * HH * NN * 4;
    float*  lbuf  = (float*)(ws + off);           off += (size_t)BB * HH * NN * 4;
    int*    flag  = (int*)(ws + off);

    float* out_o = (float*)d_out;                  // [B,N,E]
    float* out_w = out_o + (size_t)BB * NN * EE;   // [B,N,N]

    k_zero_flag<<<1, 1, 0, stream>>>(flag);
    k_maskflag<<<1024, 256, 0, stream>>>(mask, flag);

    dim3 gw(EE / 64, EE / 64);
    k_convW<<<gw, 256, 0, stream>>>(Wq,  WqTh, WqTl);
    k_convW<<<gw, 256, 0, stream>>>(Wkv, WkTh, WkTl);
    k_convW<<<gw, 256, 0, stream>>>(Wo,  WoTh, WoTl);

    dim3 gg(EE / 128, (BB * NN) / 64);   // (8, 64) = 512 blocks
    // qp: bf16 hi, folded SCALE, swizzled
    k_mgemm<0,1,0,0><<<gg, 256, 0, stream>>>(q, WqTh, WqTl, bq, SCALE,
                                             nullptr, qp_hi, nullptr, nullptr);
    // kp: bf16 hi+lo, swizzled
    k_mgemm<0,1,1,0><<<gg, 256, 0, stream>>>(k, WkTh, WkTl, bkv, 1.f,
                                             nullptr, kp_hi, kp_lo, nullptr);
    // vp: f32 + fused transposed bf16 hi (vT)
    k_mgemm<1,0,0,1><<<gg, 256, 0, stream>>>(v, WkTh, WkTl, bkv, 1.f,
                                             vp, nullptr, nullptr, vT_hi);

    k_attn<<<dim3(NN / 128 * BB * HH), 256, 0, stream>>>(qp_hi, kp_hi, kp_lo, vT_hi,
                                                         vp, alpha, mask, flag,
                                                         mbuf, lbuf, oatt);
    k_wsum<<<dim3((NN / 64) * (NN / 64) * BB), 256, 0, stream>>>(qp_hi, kp_hi, kp_lo,
                                                                 mask, flag, mbuf, lbuf, out_w);

    // out = oatt @ Wo + bo   (alpha*vp already folded into oatt by k_attn)
    k_mgemm<1,0,0,0><<<gg, 256, 0, stream>>>(oatt, WoTh, WoTl, bo, 1.f,
                                             out_o, nullptr, nullptr, nullptr);
}